// Round 6
// baseline (823.074 us; speedup 1.0000x reference)
//
#include <hip/hip_runtime.h>

// Problem constants: B=4, T=2048, C=2048, H=16, D=128
#define T_SEQ 2048
#define DHEAD 128
#define NHEAD 16
#define CDIM  2048
#define BATCH 4

typedef __bf16 v8bf __attribute__((ext_vector_type(8)));
typedef __bf16 v4bf __attribute__((ext_vector_type(4)));
typedef float  v4f  __attribute__((ext_vector_type(4)));

#define MFMA16(a,b,c) __builtin_amdgcn_mfma_f32_16x16x32_bf16(a,b,c,0,0,0)
#define GLDS16(g,l) __builtin_amdgcn_global_load_lds( \
    (__attribute__((address_space(1))) void*)(g), \
    (__attribute__((address_space(3))) void*)(l), 16, 0, 0)

// ---------------- f32 -> bf16 convert (vectorized, grid-stride) --------------
__global__ __launch_bounds__(256) void cvt_f32_bf16(const float* __restrict__ in,
                                                    __bf16* __restrict__ out, int n) {
  int i = blockIdx.x * 256 + threadIdx.x;
  int stride = gridDim.x * 256;
  for (int j = i; 4 * j < n; j += stride) {
    float4 v = *(const float4*)(in + (size_t)j * 4);
    v4bf o = {(__bf16)v.x, (__bf16)v.y, (__bf16)v.z, (__bf16)v.w};
    *(v4bf*)(out + (size_t)j * 4) = o;
  }
}

// =============== 256x256 8-phase GEMM core (m201 template, plain HIP) =======
#define LGKM0() { asm volatile("s_waitcnt lgkmcnt(0)" ::: "memory"); \
                  __builtin_amdgcn_sched_barrier(0); }
#define BARR()  { __builtin_amdgcn_s_barrier(); __builtin_amdgcn_sched_barrier(0); }

#define RDA(mm, kk) (*(const v8bf*)(bA + (wm16 + (mm)*32 + lr) * 128 + ((((kk)*64) + lgc) ^ swl)))
#define RDB(n, kk)  (*(const v8bf*)(bB + (wn64 + (n)*16 + lr) * 128 + ((((kk)*64) + lgc) ^ swl)))
#define MF(mm,n,kk) acc[mm][n] = MFMA16(af[(mm)&1][kk], bfr[n][kk], acc[mm][n]);

#define PH_MFMA(MM0, MM1) \
  BARR(); LGKM0(); \
  __builtin_amdgcn_s_setprio(1); \
  MF(MM0,0,0) MF(MM0,1,0) MF(MM0,2,0) MF(MM0,3,0) \
  MF(MM1,0,0) MF(MM1,1,0) MF(MM1,2,0) MF(MM1,3,0) \
  MF(MM0,0,1) MF(MM0,1,1) MF(MM0,2,1) MF(MM0,3,1) \
  MF(MM1,0,1) MF(MM1,1,1) MF(MM1,2,1) MF(MM1,3,1) \
  __builtin_amdgcn_s_setprio(0); \
  BARR();

#define STAGE_H(SRC, ks, hh, LBASE) { \
  GLDS16((SRC) + (size_t)((hh)*128)      * 2048 + (size_t)(ks)*64, lds + (LBASE) + dst0); \
  GLDS16((SRC) + (size_t)((hh)*128 + 64) * 2048 + (size_t)(ks)*64, lds + (LBASE) + 4096 + dst0); }

#define TILE(CB, ks1, ks2) { \
  const char* bA = (const char*)(lds + (CB)*32768); \
  const char* bB = bA + 32768; \
  v8bf bfr[4][2], af[2][2]; \
  af[0][0]=RDA(0,0); af[0][1]=RDA(0,1); af[1][0]=RDA(1,0); af[1][1]=RDA(1,1); \
  bfr[0][0]=RDB(0,0); bfr[0][1]=RDB(0,1); bfr[1][0]=RDB(1,0); bfr[1][1]=RDB(1,1); \
  bfr[2][0]=RDB(2,0); bfr[2][1]=RDB(2,1); bfr[3][0]=RDB(3,0); bfr[3][1]=RDB(3,1); \
  STAGE_H(Asrc, ks1, 1, ((CB)^1)*32768 + 8192); \
  PH_MFMA(0, 1) \
  af[0][0]=RDA(2,0); af[0][1]=RDA(2,1); af[1][0]=RDA(3,0); af[1][1]=RDA(3,1); \
  STAGE_H(Bsrc, ks2, 0, (CB)*32768 + 16384); \
  PH_MFMA(2, 3) \
  af[0][0]=RDA(4,0); af[0][1]=RDA(4,1); af[1][0]=RDA(5,0); af[1][1]=RDA(5,1); \
  STAGE_H(Asrc, ks2, 0, (CB)*32768); \
  PH_MFMA(4, 5) \
  af[0][0]=RDA(6,0); af[0][1]=RDA(6,1); af[1][0]=RDA(7,0); af[1][1]=RDA(7,1); \
  STAGE_H(Bsrc, ks2, 1, (CB)*32768 + 24576); \
  asm volatile("s_waitcnt vmcnt(6)" ::: "memory"); \
  PH_MFMA(6, 7) \
}

__device__ __forceinline__ void gemm256_core(
    const __bf16* __restrict__ A, const __bf16* __restrict__ Bm,
    int row0, int col0, __bf16* lds, v4f (&acc)[8][4],
    int wm16, int wn64, int lr, int lg) {
  int t = threadIdx.x;
  int wid = t >> 6;
  int lgc = lg * 16;
  int swl = (lr & 7) << 4;
#pragma unroll
  for (int mm = 0; mm < 8; ++mm)
#pragma unroll
    for (int n = 0; n < 4; ++n) acc[mm][n] = (v4f){0.f, 0.f, 0.f, 0.f};

  int srow = t >> 3;
  int scol = (((t & 7) ^ ((t >> 3) & 7)) << 3);
  const __bf16* Asrc = A  + (size_t)(row0 + srow) * 2048 + scol;
  const __bf16* Bsrc = Bm + (size_t)(col0 + srow) * 2048 + scol;
  int dst0 = wid << 9;

  STAGE_H(Asrc, 0, 0, 0);
  STAGE_H(Asrc, 0, 1, 8192);
  STAGE_H(Bsrc, 0, 0, 16384);
  STAGE_H(Bsrc, 0, 1, 24576);
  STAGE_H(Bsrc, 1, 0, 32768 + 16384);
  STAGE_H(Asrc, 1, 0, 32768);
  STAGE_H(Bsrc, 1, 1, 32768 + 24576);
  asm volatile("s_waitcnt vmcnt(6)" ::: "memory");
  BARR();

  for (int m = 0; m < 32; m += 2) {
    TILE(0, m + 1, (m + 2) & 31)
    TILE(1, (m + 2) & 31, (m + 3) & 31)
  }
  asm volatile("s_waitcnt vmcnt(0)" ::: "memory");
}

// GEMM1: qkv = x * w_attn^T + b_attn; scatter epilogue -> Q,K (BH,T,D), Vt (BH,D,T)
__global__ __launch_bounds__(512, 2) void gemm_qkv8(
    const __bf16* __restrict__ A, const __bf16* __restrict__ Bm,
    const float* __restrict__ bias,
    __bf16* __restrict__ Qb, __bf16* __restrict__ Kb, __bf16* __restrict__ Vt) {
  extern __shared__ __bf16 lds[];
  int t = threadIdx.x, wid = t >> 6, l = t & 63;
  int lr = l & 15, lg = l >> 4;
  int wm16 = (wid >> 2) * 16, wn64 = (wid & 3) * 64;
  int row0 = blockIdx.x * 256, col0 = blockIdx.y * 256;
  v4f acc[8][4];
  gemm256_core(A, Bm, row0, col0, lds, acc, wm16, wn64, lr, lg);

  if (col0 >= 4096) {
    // ---- V blocks: LDS-transposed coalesced store to Vt (BH,D,T) ----
    // Row stride 40 elems = 80 B (16B-aligned v8bf reads).
    // BUGFIX r6: t-coordinate is (row0 & 2047), NOT row0 — bb already
    // carries the batch. r4/r5 wrote batches 1-3 out of place (absmax 4.39).
    int h0 = (col0 & 2047) >> 7;
    int bb = row0 >> 11;
    int t0 = row0 & 2047;
    int d_r = t >> 1, half = t & 1;
    int hh = h0 + (d_r >> 7), dd = d_r & 127;
#pragma unroll
    for (int mm = 0; mm < 8; ++mm) {
      __syncthreads();   // first: all waves past vmcnt(0); later: prev reads done
#pragma unroll
      for (int n = 0; n < 4; ++n) {
        int d_loc = wn64 + n * 16 + lr;
        float bv = bias[col0 + d_loc];
        v4bf pv = {(__bf16)(acc[mm][n][0] + bv), (__bf16)(acc[mm][n][1] + bv),
                   (__bf16)(acc[mm][n][2] + bv), (__bf16)(acc[mm][n][3] + bv)};
        *(v4bf*)&lds[d_loc * 40 + wm16 + lg * 4] = pv;
      }
      __syncthreads();
      size_t vbase = ((size_t)((bb * NHEAD + hh) * DHEAD + dd)) * T_SEQ
                   + t0 + mm * 32 + half * 16;
      v8bf x0 = *(const v8bf*)&lds[d_r * 40 + half * 16];
      v8bf x1 = *(const v8bf*)&lds[d_r * 40 + half * 16 + 8];
      *(v8bf*)&Vt[vbase] = x0;
      *(v8bf*)&Vt[vbase + 8] = x1;
    }
    return;
  }
#pragma unroll
  for (int n = 0; n < 4; ++n) {
    int col = col0 + wn64 + n * 16 + lr;
    int tensor = col >> 11;
    int wc = col & 2047;
    int h = wc >> 7, d = wc & 127;
    float bv = bias[col];
#pragma unroll
    for (int mm = 0; mm < 8; ++mm) {
#pragma unroll
      for (int rr = 0; rr < 4; ++rr) {
        int mg = row0 + wm16 + mm * 32 + lg * 4 + rr;
        int b = mg >> 11, tt = mg & 2047;
        float v = acc[mm][n][rr] + bv;
        size_t bh = (size_t)(b * NHEAD + h);
        if (tensor == 0) Qb[(bh * T_SEQ + tt) * DHEAD + d] = (__bf16)v;
        else             Kb[(bh * T_SEQ + tt) * DHEAD + d] = (__bf16)v;
      }
    }
  }
}

// GEMM2: out = Y * w_proj^T + b_proj, fp32 row-major epilogue
__global__ __launch_bounds__(512, 2) void gemm_out8(
    const __bf16* __restrict__ A, const __bf16* __restrict__ Bm,
    const float* __restrict__ bias, float* __restrict__ C) {
  extern __shared__ __bf16 lds[];
  int t = threadIdx.x, wid = t >> 6, l = t & 63;
  int lr = l & 15, lg = l >> 4;
  int wm16 = (wid >> 2) * 16, wn64 = (wid & 3) * 64;
  int row0 = blockIdx.x * 256, col0 = blockIdx.y * 256;
  v4f acc[8][4];
  gemm256_core(A, Bm, row0, col0, lds, acc, wm16, wn64, lr, lg);
#pragma unroll
  for (int n = 0; n < 4; ++n) {
    int col = col0 + wn64 + n * 16 + lr;
    float bv = bias[col];
#pragma unroll
    for (int mm = 0; mm < 8; ++mm) {
#pragma unroll
      for (int rr = 0; rr < 4; ++rr) {
        int mg = row0 + wm16 + mm * 32 + lg * 4 + rr;
        C[(size_t)mg * CDIM + col] = acc[mm][n][rr] + bv;
      }
    }
  }
}

// ---------------- RoPE in-place on Q,K (BH,T,D) ------------------------------
__global__ __launch_bounds__(256) void rope_kernel(__bf16* __restrict__ Qb,
                                                   __bf16* __restrict__ Kb) {
  int idx = blockIdx.x * 256 + threadIdx.x;
  __bf16* base = (idx & 131072) ? Kb : Qb;
  int r = idx & 131071;
  int tt = r & (T_SEQ - 1);
  __bf16* p = base + (size_t)r * DHEAD;
  v8bf xv[16];
#pragma unroll
  for (int j = 0; j < 16; ++j) xv[j] = *(const v8bf*)&p[j * 8];
  v8bf ov[16];
#pragma unroll
  for (int j = 0; j < 64; ++j) {
    float invf = exp2f((float)j * (-13.287712379549449f / 64.f));
    float ang = (float)tt * invf;
    float c = cosf(ang), s = sinf(ang);
    float cps = c + s, cms = c - s;
    float xj   = (float)xv[j >> 3][j & 7];
    float xj64 = (float)xv[(j + 64) >> 3][j & 7];
    float x2j  = (float)xv[(2 * j) >> 3][(2 * j) & 7];
    float x2j1 = (float)xv[(2 * j + 1) >> 3][(2 * j + 1) & 7];
    ov[j >> 3][j & 7]        = (__bf16)(xj * cps - x2j1 * cms);
    ov[(j + 64) >> 3][j & 7] = (__bf16)(xj64 * cps + x2j * cms);
  }
#pragma unroll
  for (int j = 0; j < 16; ++j) *(v8bf*)&p[j * 8] = ov[j];
}

// ---------------- flash attention v3 -----------------------------------------
// 512 thr = 8 waves, block covers 256 q-rows (wave w: 32 rows at qb + w*32).
// K/V tile (64 kv) staged once per block into LDS (swizzled); P via per-wave
// LDS. exp2-domain softmax, defer-max (THR=8 in log2), masked-compare only on
// diagonal tiles, wave-level skip of fully-masked tiles. Bijective XCD swizzle.
__global__ __launch_bounds__(512, 4) void attn_fwd(
    const __bf16* __restrict__ Qb, const __bf16* __restrict__ Kb,
    const __bf16* __restrict__ Vt, __bf16* __restrict__ Y) {
  __shared__ __bf16 lK[64 * 128];       // 16 KB, [kv][d] swizzled
  __shared__ __bf16 lV[128 * 64];       // 16 KB, [d][kv] swizzled
  __shared__ __bf16 plds[8][32][72];    // 36 KB, per-wave P, padded rows
  int t = threadIdx.x, w = t >> 6, l = t & 63;
  int lr = l & 15, lg = l >> 4;
  int id = blockIdx.x;                        // 0..511
  int lid = (id & 7) * 64 + (id >> 3);        // XCD swizzle (512 % 8 == 0)
  int bh = lid >> 3;
  int b = bh >> 4, h = bh & 15;
  int qb = (7 - (lid & 7)) * 256;             // heavy-first within XCD chunk
  int q0 = qb + w * 32;
  const __bf16* Qh = Qb + (size_t)bh * T_SEQ * DHEAD;
  const __bf16* Kh = Kb + (size_t)bh * T_SEQ * DHEAD;
  const __bf16* Vh = Vt + (size_t)bh * DHEAD * T_SEQ;

  v8bf qf[2][4];
#pragma unroll
  for (int j = 0; j < 2; ++j)
#pragma unroll
    for (int c = 0; c < 4; ++c)
      qf[j][c] = *(const v8bf*)&Qh[(size_t)(q0 + j * 16 + lr) * DHEAD + c * 32 + lg * 8];

  v4f o[2][8];
#pragma unroll
  for (int j = 0; j < 2; ++j)
#pragma unroll
    for (int c = 0; c < 8; ++c) o[j][c] = (v4f){0.f, 0.f, 0.f, 0.f};
  float mrow[2] = {-1e30f, -1e30f}, lrow[2] = {0.f, 0.f};
  const float SCALE2 = 0.12751743f;   // (1/sqrt(128)) * log2(e)

  int kRow = t >> 4;                                       // 0..31
  int kSrc = (((t & 15) * 16) ^ ((kRow & 7) << 4)) >> 1;
  int vRow = t >> 3;                                       // 0..63
  int vSrc = (((t & 7) * 16) ^ ((vRow & 7) << 4)) >> 1;

  int kvEnd = qb + 192;
  for (int kv0 = 0; kv0 <= kvEnd; kv0 += 64) {
    __syncthreads();
#pragma unroll
    for (int i = 0; i < 2; ++i) {
      GLDS16(Kh + (size_t)(kv0 + i * 32 + kRow) * DHEAD + kSrc, lK + i * 4096 + w * 512);
      GLDS16(Vh + (size_t)(i * 64 + vRow) * T_SEQ + kv0 + vSrc, lV + i * 4096 + w * 512);
    }
    __syncthreads();

    if (kv0 <= q0 + 31) {
      // ---- QK^T (swapped): S[64 kv][32 q] ----
      v4f s[2][4];
#pragma unroll
      for (int j = 0; j < 2; ++j)
#pragma unroll
        for (int f = 0; f < 4; ++f) s[j][f] = (v4f){0.f, 0.f, 0.f, 0.f};
#pragma unroll
      for (int f = 0; f < 4; ++f) {
        int row = f * 16 + lr;
        int sw = (row & 7) << 4;
#pragma unroll
        for (int c = 0; c < 4; ++c) {
          v8bf kf = *(const v8bf*)((const char*)lK + row * 256 + ((c * 64 + lg * 16) ^ sw));
          s[0][f] = MFMA16(kf, qf[0][c], s[0][f]);
          s[1][f] = MFMA16(kf, qf[1][c], s[1][f]);
        }
      }

      v8bf pa[2][2];
#pragma unroll
      for (int j = 0; j < 2; ++j) {
        int qg = q0 + j * 16 + lr;
        bool needMask = (kv0 + 63 > q0 + j * 16);
        float p[16];
        float mt = -1e30f;
#pragma unroll
        for (int f = 0; f < 4; ++f)
#pragma unroll
          for (int r = 0; r < 4; ++r) {
            float v = s[j][f][r] * SCALE2;
            if (needMask && (kv0 + f * 16 + lg * 4 + r > qg)) v = -1e30f;
            p[f * 4 + r] = v;
            mt = fmaxf(mt, v);
          }
        mt = fmaxf(mt, __shfl_xor(mt, 16));
        mt = fmaxf(mt, __shfl_xor(mt, 32));
        if (!__all(mt <= mrow[j] + 8.0f)) {      // rescale (rare after warmup)
          float mnew = fmaxf(mrow[j], mt);
          float corr = exp2f(mrow[j] - mnew);
          mrow[j] = mnew;
          lrow[j] *= corr;
          float cf[4];
#pragma unroll
          for (int r = 0; r < 4; ++r) cf[r] = __shfl(corr, lg * 4 + r);
#pragma unroll
          for (int c = 0; c < 8; ++c)
#pragma unroll
            for (int r = 0; r < 4; ++r) o[j][c][r] *= cf[r];
        }
        float psum = 0.f;
#pragma unroll
        for (int r = 0; r < 16; ++r) { p[r] = exp2f(p[r] - mrow[j]); psum += p[r]; }
        psum += __shfl_xor(psum, 16);
        psum += __shfl_xor(psum, 32);
        lrow[j] += psum;
#pragma unroll
        for (int f = 0; f < 4; ++f) {
          v4bf pv = {(__bf16)p[f * 4], (__bf16)p[f * 4 + 1],
                     (__bf16)p[f * 4 + 2], (__bf16)p[f * 4 + 3]};
          *(v4bf*)&plds[w][j * 16 + lr][f * 16 + lg * 4] = pv;
        }
        asm volatile("s_waitcnt lgkmcnt(0)" ::: "memory");
        pa[j][0] = *(const v8bf*)&plds[w][j * 16 + lr][lg * 8];
        pa[j][1] = *(const v8bf*)&plds[w][j * 16 + lr][32 + lg * 8];
      }

      // ---- PV ----
#pragma unroll
      for (int c = 0; c < 8; ++c) {
        int row = c * 16 + lr;
        int sw = (row & 7) << 4;
        v8bf vf0 = *(const v8bf*)((const char*)lV + row * 128 + ((lg * 16) ^ sw));
        v8bf vf1 = *(const v8bf*)((const char*)lV + row * 128 + ((64 + lg * 16) ^ sw));
        o[0][c] = MFMA16(pa[0][0], vf0, o[0][c]);
        o[0][c] = MFMA16(pa[0][1], vf1, o[0][c]);
        o[1][c] = MFMA16(pa[1][0], vf0, o[1][c]);
        o[1][c] = MFMA16(pa[1][1], vf1, o[1][c]);
      }
    }
  }

  size_t ybase = ((size_t)b * T_SEQ) * CDIM + (size_t)h * DHEAD;
#pragma unroll
  for (int j = 0; j < 2; ++j) {
    float lf[4];
#pragma unroll
    for (int r = 0; r < 4; ++r) lf[r] = __shfl(lrow[j], lg * 4 + r);
#pragma unroll
    for (int c = 0; c < 8; ++c) {
#pragma unroll
      for (int r = 0; r < 4; ++r) {
        int qq = q0 + j * 16 + lg * 4 + r;
        Y[ybase + (size_t)qq * CDIM + c * 16 + lr] = (__bf16)(o[j][c][r] / lf[r]);
      }
    }
  }
}

// ---------------- launch -----------------------------------------------------
extern "C" void kernel_launch(void* const* d_in, const int* in_sizes, int n_in,
                              void* d_out, int out_size, void* d_ws, size_t ws_size,
                              hipStream_t stream) {
  const float* x      = (const float*)d_in[0];
  const float* w_attn = (const float*)d_in[1];
  const float* b_attn = (const float*)d_in[2];
  const float* w_proj = (const float*)d_in[3];
  const float* b_proj = (const float*)d_in[4];
  float* out = (float*)d_out;

  char* ws = (char*)d_ws;
  __bf16* xbf  = (__bf16*)(ws);                 // 33,554,432 B; reused as Y
  __bf16* wabf = (__bf16*)(ws + 33554432);      // 25,165,824 B
  __bf16* wpbf = (__bf16*)(ws + 58720256);      //  8,388,608 B
  __bf16* Qb   = (__bf16*)(ws + 67108864);      // 33,554,432 B (BH,T,D)
  __bf16* Kb   = (__bf16*)(ws + 100663296);     // 33,554,432 B (BH,T,D)
  __bf16* Vt   = (__bf16*)(ws + 134217728);     // 33,554,432 B (BH,D,T)
  __bf16* Y    = xbf;

  (void)hipFuncSetAttribute((const void*)gemm_qkv8,
                            hipFuncAttributeMaxDynamicSharedMemorySize, 131072);
  (void)hipFuncSetAttribute((const void*)gemm_out8,
                            hipFuncAttributeMaxDynamicSharedMemorySize, 131072);

  cvt_f32_bf16<<<1024, 256, 0, stream>>>(x, xbf, 16777216);
  cvt_f32_bf16<<<1024, 256, 0, stream>>>(w_attn, wabf, 12582912);
  cvt_f32_bf16<<<512, 256, 0, stream>>>(w_proj, wpbf, 4194304);

  gemm_qkv8<<<dim3(32, 24), 512, 131072, stream>>>(xbf, wabf, b_attn, Qb, Kb, Vt);

  rope_kernel<<<1024, 256, 0, stream>>>(Qb, Kb);

  attn_fwd<<<512, 512, 0, stream>>>(Qb, Kb, Vt, Y);

  gemm_out8<<<dim3(32, 8), 512, 131072, stream>>>(Y, wpbf, b_proj, out);
}

// Round 7
// 617.943 us; speedup vs baseline: 1.3320x; 1.3320x over previous
//
#include <hip/hip_runtime.h>

// Problem constants: B=4, T=2048, C=2048, H=16, D=128
#define T_SEQ 2048
#define DHEAD 128
#define NHEAD 16
#define CDIM  2048
#define BATCH 4

typedef __bf16 v8bf __attribute__((ext_vector_type(8)));
typedef __bf16 v4bf __attribute__((ext_vector_type(4)));
typedef float  v4f  __attribute__((ext_vector_type(4)));

#define MFMA16(a,b,c) __builtin_amdgcn_mfma_f32_16x16x32_bf16(a,b,c,0,0,0)
#define GLDS16(g,l) __builtin_amdgcn_global_load_lds( \
    (__attribute__((address_space(1))) void*)(g), \
    (__attribute__((address_space(3))) void*)(l), 16, 0, 0)

// ---------------- f32 -> bf16 convert (vectorized, grid-stride) --------------
__global__ __launch_bounds__(256) void cvt_f32_bf16(const float* __restrict__ in,
                                                    __bf16* __restrict__ out, int n) {
  int i = blockIdx.x * 256 + threadIdx.x;
  int stride = gridDim.x * 256;
  for (int j = i; 4 * j < n; j += stride) {
    float4 v = *(const float4*)(in + (size_t)j * 4);
    v4bf o = {(__bf16)v.x, (__bf16)v.y, (__bf16)v.z, (__bf16)v.w};
    *(v4bf*)(out + (size_t)j * 4) = o;
  }
}

// =============== 256x256 8-phase GEMM core (m201 template, plain HIP) =======
#define LGKM0() { asm volatile("s_waitcnt lgkmcnt(0)" ::: "memory"); \
                  __builtin_amdgcn_sched_barrier(0); }
#define BARR()  { __builtin_amdgcn_s_barrier(); __builtin_amdgcn_sched_barrier(0); }

#define RDA(mm, kk) (*(const v8bf*)(bA + (wm16 + (mm)*32 + lr) * 128 + ((((kk)*64) + lgc) ^ swl)))
#define RDB(n, kk)  (*(const v8bf*)(bB + (wn64 + (n)*16 + lr) * 128 + ((((kk)*64) + lgc) ^ swl)))
#define MF(mm,n,kk) acc[mm][n] = MFMA16(af[(mm)&1][kk], bfr[n][kk], acc[mm][n]);

#define PH_MFMA(MM0, MM1) \
  BARR(); LGKM0(); \
  __builtin_amdgcn_s_setprio(1); \
  MF(MM0,0,0) MF(MM0,1,0) MF(MM0,2,0) MF(MM0,3,0) \
  MF(MM1,0,0) MF(MM1,1,0) MF(MM1,2,0) MF(MM1,3,0) \
  MF(MM0,0,1) MF(MM0,1,1) MF(MM0,2,1) MF(MM0,3,1) \
  MF(MM1,0,1) MF(MM1,1,1) MF(MM1,2,1) MF(MM1,3,1) \
  __builtin_amdgcn_s_setprio(0); \
  BARR();

#define STAGE_H(SRC, ks, hh, LBASE) { \
  GLDS16((SRC) + (size_t)((hh)*128)      * 2048 + (size_t)(ks)*64, lds + (LBASE) + dst0); \
  GLDS16((SRC) + (size_t)((hh)*128 + 64) * 2048 + (size_t)(ks)*64, lds + (LBASE) + 4096 + dst0); }

#define TILE(CB, ks1, ks2) { \
  const char* bA = (const char*)(lds + (CB)*32768); \
  const char* bB = bA + 32768; \
  v8bf bfr[4][2], af[2][2]; \
  af[0][0]=RDA(0,0); af[0][1]=RDA(0,1); af[1][0]=RDA(1,0); af[1][1]=RDA(1,1); \
  bfr[0][0]=RDB(0,0); bfr[0][1]=RDB(0,1); bfr[1][0]=RDB(1,0); bfr[1][1]=RDB(1,1); \
  bfr[2][0]=RDB(2,0); bfr[2][1]=RDB(2,1); bfr[3][0]=RDB(3,0); bfr[3][1]=RDB(3,1); \
  STAGE_H(Asrc, ks1, 1, ((CB)^1)*32768 + 8192); \
  PH_MFMA(0, 1) \
  af[0][0]=RDA(2,0); af[0][1]=RDA(2,1); af[1][0]=RDA(3,0); af[1][1]=RDA(3,1); \
  STAGE_H(Bsrc, ks2, 0, (CB)*32768 + 16384); \
  PH_MFMA(2, 3) \
  af[0][0]=RDA(4,0); af[0][1]=RDA(4,1); af[1][0]=RDA(5,0); af[1][1]=RDA(5,1); \
  STAGE_H(Asrc, ks2, 0, (CB)*32768); \
  PH_MFMA(4, 5) \
  af[0][0]=RDA(6,0); af[0][1]=RDA(6,1); af[1][0]=RDA(7,0); af[1][1]=RDA(7,1); \
  STAGE_H(Bsrc, ks2, 1, (CB)*32768 + 24576); \
  asm volatile("s_waitcnt vmcnt(6)" ::: "memory"); \
  PH_MFMA(6, 7) \
}

__device__ __forceinline__ void gemm256_core(
    const __bf16* __restrict__ A, const __bf16* __restrict__ Bm,
    int row0, int col0, __bf16* lds, v4f (&acc)[8][4],
    int wm16, int wn64, int lr, int lg) {
  int t = threadIdx.x;
  int wid = t >> 6;
  int lgc = lg * 16;
  int swl = (lr & 7) << 4;
#pragma unroll
  for (int mm = 0; mm < 8; ++mm)
#pragma unroll
    for (int n = 0; n < 4; ++n) acc[mm][n] = (v4f){0.f, 0.f, 0.f, 0.f};

  int srow = t >> 3;
  int scol = (((t & 7) ^ ((t >> 3) & 7)) << 3);
  const __bf16* Asrc = A  + (size_t)(row0 + srow) * 2048 + scol;
  const __bf16* Bsrc = Bm + (size_t)(col0 + srow) * 2048 + scol;
  int dst0 = wid << 9;

  STAGE_H(Asrc, 0, 0, 0);
  STAGE_H(Asrc, 0, 1, 8192);
  STAGE_H(Bsrc, 0, 0, 16384);
  STAGE_H(Bsrc, 0, 1, 24576);
  STAGE_H(Bsrc, 1, 0, 32768 + 16384);
  STAGE_H(Asrc, 1, 0, 32768);
  STAGE_H(Bsrc, 1, 1, 32768 + 24576);
  asm volatile("s_waitcnt vmcnt(6)" ::: "memory");
  BARR();

  for (int m = 0; m < 32; m += 2) {
    TILE(0, m + 1, (m + 2) & 31)
    TILE(1, (m + 2) & 31, (m + 3) & 31)
  }
  asm volatile("s_waitcnt vmcnt(0)" ::: "memory");
}

// GEMM1: qkv = x * w_attn^T + b_attn; scatter epilogue -> Q,K (BH,T,D), Vt (BH,D,T)
__global__ __launch_bounds__(512, 2) void gemm_qkv8(
    const __bf16* __restrict__ A, const __bf16* __restrict__ Bm,
    const float* __restrict__ bias,
    __bf16* __restrict__ Qb, __bf16* __restrict__ Kb, __bf16* __restrict__ Vt) {
  extern __shared__ __bf16 lds[];
  int t = threadIdx.x, wid = t >> 6, l = t & 63;
  int lr = l & 15, lg = l >> 4;
  int wm16 = (wid >> 2) * 16, wn64 = (wid & 3) * 64;
  int row0 = blockIdx.x * 256, col0 = blockIdx.y * 256;
  v4f acc[8][4];
  gemm256_core(A, Bm, row0, col0, lds, acc, wm16, wn64, lr, lg);

  if (col0 >= 4096) {
    // ---- V blocks: LDS-transposed coalesced store to Vt (BH,D,T) ----
    int h0 = (col0 & 2047) >> 7;
    int bb = row0 >> 11;
    int t0 = row0 & 2047;
    int d_r = t >> 1, half = t & 1;
    int hh = h0 + (d_r >> 7), dd = d_r & 127;
#pragma unroll
    for (int mm = 0; mm < 8; ++mm) {
      __syncthreads();
#pragma unroll
      for (int n = 0; n < 4; ++n) {
        int d_loc = wn64 + n * 16 + lr;
        float bv = bias[col0 + d_loc];
        v4bf pv = {(__bf16)(acc[mm][n][0] + bv), (__bf16)(acc[mm][n][1] + bv),
                   (__bf16)(acc[mm][n][2] + bv), (__bf16)(acc[mm][n][3] + bv)};
        *(v4bf*)&lds[d_loc * 40 + wm16 + lg * 4] = pv;
      }
      __syncthreads();
      size_t vbase = ((size_t)((bb * NHEAD + hh) * DHEAD + dd)) * T_SEQ
                   + t0 + mm * 32 + half * 16;
      v8bf x0 = *(const v8bf*)&lds[d_r * 40 + half * 16];
      v8bf x1 = *(const v8bf*)&lds[d_r * 40 + half * 16 + 8];
      *(v8bf*)&Vt[vbase] = x0;
      *(v8bf*)&Vt[vbase + 8] = x1;
    }
    return;
  }
#pragma unroll
  for (int n = 0; n < 4; ++n) {
    int col = col0 + wn64 + n * 16 + lr;
    int tensor = col >> 11;
    int wc = col & 2047;
    int h = wc >> 7, d = wc & 127;
    float bv = bias[col];
#pragma unroll
    for (int mm = 0; mm < 8; ++mm) {
#pragma unroll
      for (int rr = 0; rr < 4; ++rr) {
        int mg = row0 + wm16 + mm * 32 + lg * 4 + rr;
        int b = mg >> 11, tt = mg & 2047;
        float v = acc[mm][n][rr] + bv;
        size_t bh = (size_t)(b * NHEAD + h);
        if (tensor == 0) Qb[(bh * T_SEQ + tt) * DHEAD + d] = (__bf16)v;
        else             Kb[(bh * T_SEQ + tt) * DHEAD + d] = (__bf16)v;
      }
    }
  }
}

// GEMM2: out = Y * w_proj^T + b_proj, fp32 row-major epilogue
__global__ __launch_bounds__(512, 2) void gemm_out8(
    const __bf16* __restrict__ A, const __bf16* __restrict__ Bm,
    const float* __restrict__ bias, float* __restrict__ C) {
  extern __shared__ __bf16 lds[];
  int t = threadIdx.x, wid = t >> 6, l = t & 63;
  int lr = l & 15, lg = l >> 4;
  int wm16 = (wid >> 2) * 16, wn64 = (wid & 3) * 64;
  int row0 = blockIdx.x * 256, col0 = blockIdx.y * 256;
  v4f acc[8][4];
  gemm256_core(A, Bm, row0, col0, lds, acc, wm16, wn64, lr, lg);
#pragma unroll
  for (int n = 0; n < 4; ++n) {
    int col = col0 + wn64 + n * 16 + lr;
    float bv = bias[col];
#pragma unroll
    for (int mm = 0; mm < 8; ++mm) {
#pragma unroll
      for (int rr = 0; rr < 4; ++rr) {
        int mg = row0 + wm16 + mm * 32 + lg * 4 + rr;
        C[(size_t)mg * CDIM + col] = acc[mm][n][rr] + bv;
      }
    }
  }
}

// ---------------- RoPE in-place on Q,K (BH,T,D) ------------------------------
__global__ __launch_bounds__(256) void rope_kernel(__bf16* __restrict__ Qb,
                                                   __bf16* __restrict__ Kb) {
  int idx = blockIdx.x * 256 + threadIdx.x;
  __bf16* base = (idx & 131072) ? Kb : Qb;
  int r = idx & 131071;
  int tt = r & (T_SEQ - 1);
  __bf16* p = base + (size_t)r * DHEAD;
  v8bf xv[16];
#pragma unroll
  for (int j = 0; j < 16; ++j) xv[j] = *(const v8bf*)&p[j * 8];
  v8bf ov[16];
#pragma unroll
  for (int j = 0; j < 64; ++j) {
    float invf = exp2f((float)j * (-13.287712379549449f / 64.f));
    float ang = (float)tt * invf;
    float c = cosf(ang), s = sinf(ang);
    float cps = c + s, cms = c - s;
    float xj   = (float)xv[j >> 3][j & 7];
    float xj64 = (float)xv[(j + 64) >> 3][j & 7];
    float x2j  = (float)xv[(2 * j) >> 3][(2 * j) & 7];
    float x2j1 = (float)xv[(2 * j + 1) >> 3][(2 * j + 1) & 7];
    ov[j >> 3][j & 7]        = (__bf16)(xj * cps - x2j1 * cms);
    ov[(j + 64) >> 3][j & 7] = (__bf16)(xj64 * cps + x2j * cms);
  }
#pragma unroll
  for (int j = 0; j < 16; ++j) *(v8bf*)&p[j * 8] = ov[j];
}

// ---------------- flash attention v3 -----------------------------------------
// 512 thr = 8 waves, block covers 256 q-rows (wave w: 32 rows at qb + w*32).
// K/V tile (64 kv) staged once per block into LDS (swizzled); P via per-wave
// LDS. exp2-domain softmax, defer-max, mask only on diagonal tiles, wave-level
// skip of fully-masked tiles. Bijective XCD swizzle.
// BUGFIX r7: launch_bounds (512,4) acted as 4 blocks/CU -> 8 waves/SIMD ->
// VGPR capped at 64 -> massive scratch spill (WRITE_SIZE 645 MB, 436 us).
// (512,2) -> VGPR cap 128 (r3 evidence: this working set fits in 124).
__global__ __launch_bounds__(512, 2) void attn_fwd(
    const __bf16* __restrict__ Qb, const __bf16* __restrict__ Kb,
    const __bf16* __restrict__ Vt, __bf16* __restrict__ Y) {
  __shared__ __bf16 lK[64 * 128];       // 16 KB, [kv][d] swizzled
  __shared__ __bf16 lV[128 * 64];       // 16 KB, [d][kv] swizzled
  __shared__ __bf16 plds[8][32][72];    // 36 KB, per-wave P, padded rows
  int t = threadIdx.x, w = t >> 6, l = t & 63;
  int lr = l & 15, lg = l >> 4;
  int id = blockIdx.x;                        // 0..511
  int lid = (id & 7) * 64 + (id >> 3);        // XCD swizzle (512 % 8 == 0)
  int bh = lid >> 3;
  int b = bh >> 4, h = bh & 15;
  int qb = (7 - (lid & 7)) * 256;             // heavy-first within XCD chunk
  int q0 = qb + w * 32;
  const __bf16* Qh = Qb + (size_t)bh * T_SEQ * DHEAD;
  const __bf16* Kh = Kb + (size_t)bh * T_SEQ * DHEAD;
  const __bf16* Vh = Vt + (size_t)bh * DHEAD * T_SEQ;

  v8bf qf[2][4];
#pragma unroll
  for (int j = 0; j < 2; ++j)
#pragma unroll
    for (int c = 0; c < 4; ++c)
      qf[j][c] = *(const v8bf*)&Qh[(size_t)(q0 + j * 16 + lr) * DHEAD + c * 32 + lg * 8];

  v4f o[2][8];
#pragma unroll
  for (int j = 0; j < 2; ++j)
#pragma unroll
    for (int c = 0; c < 8; ++c) o[j][c] = (v4f){0.f, 0.f, 0.f, 0.f};
  float mrow[2] = {-1e30f, -1e30f}, lrow[2] = {0.f, 0.f};
  const float SCALE2 = 0.12751743f;   // (1/sqrt(128)) * log2(e)

  int kRow = t >> 4;                                       // 0..31
  int kSrc = (((t & 15) * 16) ^ ((kRow & 7) << 4)) >> 1;
  int vRow = t >> 3;                                       // 0..63
  int vSrc = (((t & 7) * 16) ^ ((vRow & 7) << 4)) >> 1;

  int kvEnd = qb + 192;
  for (int kv0 = 0; kv0 <= kvEnd; kv0 += 64) {
    __syncthreads();
#pragma unroll
    for (int i = 0; i < 2; ++i) {
      GLDS16(Kh + (size_t)(kv0 + i * 32 + kRow) * DHEAD + kSrc, lK + i * 4096 + w * 512);
      GLDS16(Vh + (size_t)(i * 64 + vRow) * T_SEQ + kv0 + vSrc, lV + i * 4096 + w * 512);
    }
    __syncthreads();

    if (kv0 <= q0 + 31) {
      // ---- QK^T (swapped): S[64 kv][32 q] ----
      v4f s[2][4];
#pragma unroll
      for (int j = 0; j < 2; ++j)
#pragma unroll
        for (int f = 0; f < 4; ++f) s[j][f] = (v4f){0.f, 0.f, 0.f, 0.f};
#pragma unroll
      for (int f = 0; f < 4; ++f) {
        int row = f * 16 + lr;
        int sw = (row & 7) << 4;
#pragma unroll
        for (int c = 0; c < 4; ++c) {
          v8bf kf = *(const v8bf*)((const char*)lK + row * 256 + ((c * 64 + lg * 16) ^ sw));
          s[0][f] = MFMA16(kf, qf[0][c], s[0][f]);
          s[1][f] = MFMA16(kf, qf[1][c], s[1][f]);
        }
      }

      v8bf pa[2][2];
#pragma unroll
      for (int j = 0; j < 2; ++j) {
        int qg = q0 + j * 16 + lr;
        bool needMask = (kv0 + 63 > q0 + j * 16);
        float p[16];
        float mt = -1e30f;
#pragma unroll
        for (int f = 0; f < 4; ++f)
#pragma unroll
          for (int r = 0; r < 4; ++r) {
            float v = s[j][f][r] * SCALE2;
            if (needMask && (kv0 + f * 16 + lg * 4 + r > qg)) v = -1e30f;
            p[f * 4 + r] = v;
            mt = fmaxf(mt, v);
          }
        mt = fmaxf(mt, __shfl_xor(mt, 16));
        mt = fmaxf(mt, __shfl_xor(mt, 32));
        if (!__all(mt <= mrow[j] + 8.0f)) {      // rescale (rare after warmup)
          float mnew = fmaxf(mrow[j], mt);
          float corr = exp2f(mrow[j] - mnew);
          mrow[j] = mnew;
          lrow[j] *= corr;
          float cf[4];
#pragma unroll
          for (int r = 0; r < 4; ++r) cf[r] = __shfl(corr, lg * 4 + r);
#pragma unroll
          for (int c = 0; c < 8; ++c)
#pragma unroll
            for (int r = 0; r < 4; ++r) o[j][c][r] *= cf[r];
        }
        float psum = 0.f;
#pragma unroll
        for (int r = 0; r < 16; ++r) { p[r] = exp2f(p[r] - mrow[j]); psum += p[r]; }
        psum += __shfl_xor(psum, 16);
        psum += __shfl_xor(psum, 32);
        lrow[j] += psum;
#pragma unroll
        for (int f = 0; f < 4; ++f) {
          v4bf pv = {(__bf16)p[f * 4], (__bf16)p[f * 4 + 1],
                     (__bf16)p[f * 4 + 2], (__bf16)p[f * 4 + 3]};
          *(v4bf*)&plds[w][j * 16 + lr][f * 16 + lg * 4] = pv;
        }
        asm volatile("s_waitcnt lgkmcnt(0)" ::: "memory");
        pa[j][0] = *(const v8bf*)&plds[w][j * 16 + lr][lg * 8];
        pa[j][1] = *(const v8bf*)&plds[w][j * 16 + lr][32 + lg * 8];
      }

      // ---- PV ----
#pragma unroll
      for (int c = 0; c < 8; ++c) {
        int row = c * 16 + lr;
        int sw = (row & 7) << 4;
        v8bf vf0 = *(const v8bf*)((const char*)lV + row * 128 + ((lg * 16) ^ sw));
        v8bf vf1 = *(const v8bf*)((const char*)lV + row * 128 + ((64 + lg * 16) ^ sw));
        o[0][c] = MFMA16(pa[0][0], vf0, o[0][c]);
        o[0][c] = MFMA16(pa[0][1], vf1, o[0][c]);
        o[1][c] = MFMA16(pa[1][0], vf0, o[1][c]);
        o[1][c] = MFMA16(pa[1][1], vf1, o[1][c]);
      }
    }
  }

  size_t ybase = ((size_t)b * T_SEQ) * CDIM + (size_t)h * DHEAD;
#pragma unroll
  for (int j = 0; j < 2; ++j) {
    float lf[4];
#pragma unroll
    for (int r = 0; r < 4; ++r) lf[r] = __shfl(lrow[j], lg * 4 + r);
#pragma unroll
    for (int c = 0; c < 8; ++c) {
#pragma unroll
      for (int r = 0; r < 4; ++r) {
        int qq = q0 + j * 16 + lg * 4 + r;
        Y[ybase + (size_t)qq * CDIM + c * 16 + lr] = (__bf16)(o[j][c][r] / lf[r]);
      }
    }
  }
}

// ---------------- launch -----------------------------------------------------
extern "C" void kernel_launch(void* const* d_in, const int* in_sizes, int n_in,
                              void* d_out, int out_size, void* d_ws, size_t ws_size,
                              hipStream_t stream) {
  const float* x      = (const float*)d_in[0];
  const float* w_attn = (const float*)d_in[1];
  const float* b_attn = (const float*)d_in[2];
  const float* w_proj = (const float*)d_in[3];
  const float* b_proj = (const float*)d_in[4];
  float* out = (float*)d_out;

  char* ws = (char*)d_ws;
  __bf16* xbf  = (__bf16*)(ws);                 // 33,554,432 B; reused as Y
  __bf16* wabf = (__bf16*)(ws + 33554432);      // 25,165,824 B
  __bf16* wpbf = (__bf16*)(ws + 58720256);      //  8,388,608 B
  __bf16* Qb   = (__bf16*)(ws + 67108864);      // 33,554,432 B (BH,T,D)
  __bf16* Kb   = (__bf16*)(ws + 100663296);     // 33,554,432 B (BH,T,D)
  __bf16* Vt   = (__bf16*)(ws + 134217728);     // 33,554,432 B (BH,D,T)
  __bf16* Y    = xbf;

  (void)hipFuncSetAttribute((const void*)gemm_qkv8,
                            hipFuncAttributeMaxDynamicSharedMemorySize, 131072);
  (void)hipFuncSetAttribute((const void*)gemm_out8,
                            hipFuncAttributeMaxDynamicSharedMemorySize, 131072);

  cvt_f32_bf16<<<1024, 256, 0, stream>>>(x, xbf, 16777216);
  cvt_f32_bf16<<<1024, 256, 0, stream>>>(w_attn, wabf, 12582912);
  cvt_f32_bf16<<<512, 256, 0, stream>>>(w_proj, wpbf, 4194304);

  gemm_qkv8<<<dim3(32, 24), 512, 131072, stream>>>(xbf, wabf, b_attn, Qb, Kb, Vt);

  rope_kernel<<<1024, 256, 0, stream>>>(Qb, Kb);

  attn_fwd<<<512, 512, 0, stream>>>(Qb, Kb, Vt, Y);

  gemm_out8<<<dim3(32, 8), 512, 131072, stream>>>(Y, wpbf, b_proj, out);
}

// Round 8
// 555.875 us; speedup vs baseline: 1.4807x; 1.1117x over previous
//
#include <hip/hip_runtime.h>

// Problem constants: B=4, T=2048, C=2048, H=16, D=128
#define T_SEQ 2048
#define DHEAD 128
#define NHEAD 16
#define CDIM  2048
#define BATCH 4

typedef __bf16 v8bf __attribute__((ext_vector_type(8)));
typedef __bf16 v4bf __attribute__((ext_vector_type(4)));
typedef float  v4f  __attribute__((ext_vector_type(4)));

#define MFMA16(a,b,c) __builtin_amdgcn_mfma_f32_16x16x32_bf16(a,b,c,0,0,0)
#define GLDS16(g,l) __builtin_amdgcn_global_load_lds( \
    (__attribute__((address_space(1))) void*)(g), \
    (__attribute__((address_space(3))) void*)(l), 16, 0, 0)

// ---------------- f32 -> bf16 convert (vectorized, grid-stride) --------------
__global__ __launch_bounds__(256) void cvt_f32_bf16(const float* __restrict__ in,
                                                    __bf16* __restrict__ out, int n) {
  int i = blockIdx.x * 256 + threadIdx.x;
  int stride = gridDim.x * 256;
  for (int j = i; 4 * j < n; j += stride) {
    float4 v = *(const float4*)(in + (size_t)j * 4);
    v4bf o = {(__bf16)v.x, (__bf16)v.y, (__bf16)v.z, (__bf16)v.w};
    *(v4bf*)(out + (size_t)j * 4) = o;
  }
}

// =============== 256x256 8-phase GEMM core (m201 template, plain HIP) =======
#define LGKM0() { asm volatile("s_waitcnt lgkmcnt(0)" ::: "memory"); \
                  __builtin_amdgcn_sched_barrier(0); }
#define BARR()  { __builtin_amdgcn_s_barrier(); __builtin_amdgcn_sched_barrier(0); }

#define RDA(mm, kk) (*(const v8bf*)(bA + (wm16 + (mm)*32 + lr) * 128 + ((((kk)*64) + lgc) ^ swl)))
#define RDB(n, kk)  (*(const v8bf*)(bB + (wn64 + (n)*16 + lr) * 128 + ((((kk)*64) + lgc) ^ swl)))
#define MF(mm,n,kk) acc[mm][n] = MFMA16(af[(mm)&1][kk], bfr[n][kk], acc[mm][n]);

#define PH_MFMA(MM0, MM1) \
  BARR(); LGKM0(); \
  __builtin_amdgcn_s_setprio(1); \
  MF(MM0,0,0) MF(MM0,1,0) MF(MM0,2,0) MF(MM0,3,0) \
  MF(MM1,0,0) MF(MM1,1,0) MF(MM1,2,0) MF(MM1,3,0) \
  MF(MM0,0,1) MF(MM0,1,1) MF(MM0,2,1) MF(MM0,3,1) \
  MF(MM1,0,1) MF(MM1,1,1) MF(MM1,2,1) MF(MM1,3,1) \
  __builtin_amdgcn_s_setprio(0); \
  BARR();

#define STAGE_H(SRC, ks, hh, LBASE) { \
  GLDS16((SRC) + (size_t)((hh)*128)      * 2048 + (size_t)(ks)*64, lds + (LBASE) + dst0); \
  GLDS16((SRC) + (size_t)((hh)*128 + 64) * 2048 + (size_t)(ks)*64, lds + (LBASE) + 4096 + dst0); }

#define TILE(CB, ks1, ks2) { \
  const char* bA = (const char*)(lds + (CB)*32768); \
  const char* bB = bA + 32768; \
  v8bf bfr[4][2], af[2][2]; \
  af[0][0]=RDA(0,0); af[0][1]=RDA(0,1); af[1][0]=RDA(1,0); af[1][1]=RDA(1,1); \
  bfr[0][0]=RDB(0,0); bfr[0][1]=RDB(0,1); bfr[1][0]=RDB(1,0); bfr[1][1]=RDB(1,1); \
  bfr[2][0]=RDB(2,0); bfr[2][1]=RDB(2,1); bfr[3][0]=RDB(3,0); bfr[3][1]=RDB(3,1); \
  STAGE_H(Asrc, ks1, 1, ((CB)^1)*32768 + 8192); \
  PH_MFMA(0, 1) \
  af[0][0]=RDA(2,0); af[0][1]=RDA(2,1); af[1][0]=RDA(3,0); af[1][1]=RDA(3,1); \
  STAGE_H(Bsrc, ks2, 0, (CB)*32768 + 16384); \
  PH_MFMA(2, 3) \
  af[0][0]=RDA(4,0); af[0][1]=RDA(4,1); af[1][0]=RDA(5,0); af[1][1]=RDA(5,1); \
  STAGE_H(Asrc, ks2, 0, (CB)*32768); \
  PH_MFMA(4, 5) \
  af[0][0]=RDA(6,0); af[0][1]=RDA(6,1); af[1][0]=RDA(7,0); af[1][1]=RDA(7,1); \
  STAGE_H(Bsrc, ks2, 1, (CB)*32768 + 24576); \
  asm volatile("s_waitcnt vmcnt(6)" ::: "memory"); \
  PH_MFMA(6, 7) \
}

__device__ __forceinline__ void gemm256_core(
    const __bf16* __restrict__ A, const __bf16* __restrict__ Bm,
    int row0, int col0, __bf16* lds, v4f (&acc)[8][4],
    int wm16, int wn64, int lr, int lg) {
  int t = threadIdx.x;
  int wid = t >> 6;
  int lgc = lg * 16;
  int swl = (lr & 7) << 4;
#pragma unroll
  for (int mm = 0; mm < 8; ++mm)
#pragma unroll
    for (int n = 0; n < 4; ++n) acc[mm][n] = (v4f){0.f, 0.f, 0.f, 0.f};

  int srow = t >> 3;
  int scol = (((t & 7) ^ ((t >> 3) & 7)) << 3);
  const __bf16* Asrc = A  + (size_t)(row0 + srow) * 2048 + scol;
  const __bf16* Bsrc = Bm + (size_t)(col0 + srow) * 2048 + scol;
  int dst0 = wid << 9;

  STAGE_H(Asrc, 0, 0, 0);
  STAGE_H(Asrc, 0, 1, 8192);
  STAGE_H(Bsrc, 0, 0, 16384);
  STAGE_H(Bsrc, 0, 1, 24576);
  STAGE_H(Bsrc, 1, 0, 32768 + 16384);
  STAGE_H(Asrc, 1, 0, 32768);
  STAGE_H(Bsrc, 1, 1, 32768 + 24576);
  asm volatile("s_waitcnt vmcnt(6)" ::: "memory");
  BARR();

  for (int m = 0; m < 32; m += 2) {
    TILE(0, m + 1, (m + 2) & 31)
    TILE(1, (m + 2) & 31, (m + 3) & 31)
  }
  asm volatile("s_waitcnt vmcnt(0)" ::: "memory");
}

// GEMM1: qkv = x * w_attn^T + b_attn; scatter epilogue -> Q,K (BH,T,D), Vt (BH,D,T)
__global__ __launch_bounds__(512, 2) void gemm_qkv8(
    const __bf16* __restrict__ A, const __bf16* __restrict__ Bm,
    const float* __restrict__ bias,
    __bf16* __restrict__ Qb, __bf16* __restrict__ Kb, __bf16* __restrict__ Vt) {
  extern __shared__ __bf16 lds[];
  int t = threadIdx.x, wid = t >> 6, l = t & 63;
  int lr = l & 15, lg = l >> 4;
  int wm16 = (wid >> 2) * 16, wn64 = (wid & 3) * 64;
  int row0 = blockIdx.x * 256, col0 = blockIdx.y * 256;
  v4f acc[8][4];
  gemm256_core(A, Bm, row0, col0, lds, acc, wm16, wn64, lr, lg);

  if (col0 >= 4096) {
    // ---- V blocks: LDS-transposed coalesced store to Vt (BH,D,T) ----
    int h0 = (col0 & 2047) >> 7;
    int bb = row0 >> 11;
    int t0 = row0 & 2047;
    int d_r = t >> 1, half = t & 1;
    int hh = h0 + (d_r >> 7), dd = d_r & 127;
#pragma unroll
    for (int mm = 0; mm < 8; ++mm) {
      __syncthreads();
#pragma unroll
      for (int n = 0; n < 4; ++n) {
        int d_loc = wn64 + n * 16 + lr;
        float bv = bias[col0 + d_loc];
        v4bf pv = {(__bf16)(acc[mm][n][0] + bv), (__bf16)(acc[mm][n][1] + bv),
                   (__bf16)(acc[mm][n][2] + bv), (__bf16)(acc[mm][n][3] + bv)};
        *(v4bf*)&lds[d_loc * 40 + wm16 + lg * 4] = pv;
      }
      __syncthreads();
      size_t vbase = ((size_t)((bb * NHEAD + hh) * DHEAD + dd)) * T_SEQ
                   + t0 + mm * 32 + half * 16;
      v8bf x0 = *(const v8bf*)&lds[d_r * 40 + half * 16];
      v8bf x1 = *(const v8bf*)&lds[d_r * 40 + half * 16 + 8];
      *(v8bf*)&Vt[vbase] = x0;
      *(v8bf*)&Vt[vbase + 8] = x1;
    }
    return;
  }
#pragma unroll
  for (int n = 0; n < 4; ++n) {
    int col = col0 + wn64 + n * 16 + lr;
    int tensor = col >> 11;
    int wc = col & 2047;
    int h = wc >> 7, d = wc & 127;
    float bv = bias[col];
#pragma unroll
    for (int mm = 0; mm < 8; ++mm) {
#pragma unroll
      for (int rr = 0; rr < 4; ++rr) {
        int mg = row0 + wm16 + mm * 32 + lg * 4 + rr;
        int b = mg >> 11, tt = mg & 2047;
        float v = acc[mm][n][rr] + bv;
        size_t bh = (size_t)(b * NHEAD + h);
        if (tensor == 0) Qb[(bh * T_SEQ + tt) * DHEAD + d] = (__bf16)v;
        else             Kb[(bh * T_SEQ + tt) * DHEAD + d] = (__bf16)v;
      }
    }
  }
}

// GEMM2: out = Y * w_proj^T + b_proj, fp32 row-major epilogue
__global__ __launch_bounds__(512, 2) void gemm_out8(
    const __bf16* __restrict__ A, const __bf16* __restrict__ Bm,
    const float* __restrict__ bias, float* __restrict__ C) {
  extern __shared__ __bf16 lds[];
  int t = threadIdx.x, wid = t >> 6, l = t & 63;
  int lr = l & 15, lg = l >> 4;
  int wm16 = (wid >> 2) * 16, wn64 = (wid & 3) * 64;
  int row0 = blockIdx.x * 256, col0 = blockIdx.y * 256;
  v4f acc[8][4];
  gemm256_core(A, Bm, row0, col0, lds, acc, wm16, wn64, lr, lg);
#pragma unroll
  for (int n = 0; n < 4; ++n) {
    int col = col0 + wn64 + n * 16 + lr;
    float bv = bias[col];
#pragma unroll
    for (int mm = 0; mm < 8; ++mm) {
#pragma unroll
      for (int rr = 0; rr < 4; ++rr) {
        int mg = row0 + wm16 + mm * 32 + lg * 4 + rr;
        C[(size_t)mg * CDIM + col] = acc[mm][n][rr] + bv;
      }
    }
  }
}

// ---------------- RoPE in-place on Q,K (BH,T,D) ------------------------------
__global__ __launch_bounds__(256) void rope_kernel(__bf16* __restrict__ Qb,
                                                   __bf16* __restrict__ Kb) {
  int idx = blockIdx.x * 256 + threadIdx.x;
  __bf16* base = (idx & 131072) ? Kb : Qb;
  int r = idx & 131071;
  int tt = r & (T_SEQ - 1);
  __bf16* p = base + (size_t)r * DHEAD;
  v8bf xv[16];
#pragma unroll
  for (int j = 0; j < 16; ++j) xv[j] = *(const v8bf*)&p[j * 8];
  v8bf ov[16];
#pragma unroll
  for (int j = 0; j < 64; ++j) {
    float invf = exp2f((float)j * (-13.287712379549449f / 64.f));
    float ang = (float)tt * invf;
    float c = cosf(ang), s = sinf(ang);
    float cps = c + s, cms = c - s;
    float xj   = (float)xv[j >> 3][j & 7];
    float xj64 = (float)xv[(j + 64) >> 3][j & 7];
    float x2j  = (float)xv[(2 * j) >> 3][(2 * j) & 7];
    float x2j1 = (float)xv[(2 * j + 1) >> 3][(2 * j + 1) & 7];
    ov[j >> 3][j & 7]        = (__bf16)(xj * cps - x2j1 * cms);
    ov[(j + 64) >> 3][j & 7] = (__bf16)(xj64 * cps + x2j * cms);
  }
#pragma unroll
  for (int j = 0; j < 16; ++j) *(v8bf*)&p[j * 8] = ov[j];
}

// ---------------- flash attention v4 -----------------------------------------
// 512 thr = 8 waves, block covers 256 q-rows (wave w: 32 rows at qb + w*32).
// r8: complementary CU pairing. Work per block = qb/64+4 tiles (4..32, 8x).
// Dispatch model (evidenced r7): XCD = id%8; CU gets per-XCD slots s, s+32
// (ids id, id+256) -> old map gave both the SAME qb (2x imbalance, occ 13%).
// New map: xcd=id&7, s=id>>3, bh=xcd*8+(s&7), g=s>>3, k=(g<4? 7-g : g-4),
// qb=k*256. id & id+256: same bh (K/V L2 reuse), k+k'=7 -> every CU 36 tiles.
__global__ __launch_bounds__(512, 2) void attn_fwd(
    const __bf16* __restrict__ Qb, const __bf16* __restrict__ Kb,
    const __bf16* __restrict__ Vt, __bf16* __restrict__ Y) {
  __shared__ __bf16 lK[64 * 128];       // 16 KB, [kv][d] swizzled
  __shared__ __bf16 lV[128 * 64];       // 16 KB, [d][kv] swizzled
  __shared__ __bf16 plds[8][32][72];    // 36 KB, per-wave P, padded rows
  int t = threadIdx.x, w = t >> 6, l = t & 63;
  int lr = l & 15, lg = l >> 4;
  int id = blockIdx.x;                        // 0..511
  int xcd = id & 7, s = id >> 3;
  int bh = xcd * 8 + (s & 7);
  int g = s >> 3;
  int k = (g < 4) ? (7 - g) : (g - 4);
  int qb = k * 256;
  int b = bh >> 4, h = bh & 15;
  int q0 = qb + w * 32;
  const __bf16* Qh = Qb + (size_t)bh * T_SEQ * DHEAD;
  const __bf16* Kh = Kb + (size_t)bh * T_SEQ * DHEAD;
  const __bf16* Vh = Vt + (size_t)bh * DHEAD * T_SEQ;

  v8bf qf[2][4];
#pragma unroll
  for (int j = 0; j < 2; ++j)
#pragma unroll
    for (int c = 0; c < 4; ++c)
      qf[j][c] = *(const v8bf*)&Qh[(size_t)(q0 + j * 16 + lr) * DHEAD + c * 32 + lg * 8];

  v4f o[2][8];
#pragma unroll
  for (int j = 0; j < 2; ++j)
#pragma unroll
    for (int c = 0; c < 8; ++c) o[j][c] = (v4f){0.f, 0.f, 0.f, 0.f};
  float mrow[2] = {-1e30f, -1e30f}, lrow[2] = {0.f, 0.f};
  const float SCALE2 = 0.12751743f;   // (1/sqrt(128)) * log2(e)

  int kRow = t >> 4;                                       // 0..31
  int kSrc = (((t & 15) * 16) ^ ((kRow & 7) << 4)) >> 1;
  int vRow = t >> 3;                                       // 0..63
  int vSrc = (((t & 7) * 16) ^ ((vRow & 7) << 4)) >> 1;

  int kvEnd = qb + 192;
  for (int kv0 = 0; kv0 <= kvEnd; kv0 += 64) {
    __syncthreads();
#pragma unroll
    for (int i = 0; i < 2; ++i) {
      GLDS16(Kh + (size_t)(kv0 + i * 32 + kRow) * DHEAD + kSrc, lK + i * 4096 + w * 512);
      GLDS16(Vh + (size_t)(i * 64 + vRow) * T_SEQ + kv0 + vSrc, lV + i * 4096 + w * 512);
    }
    __syncthreads();

    if (kv0 <= q0 + 31) {
      // ---- QK^T (swapped): S[64 kv][32 q] ----
      v4f s2[2][4];
#pragma unroll
      for (int j = 0; j < 2; ++j)
#pragma unroll
        for (int f = 0; f < 4; ++f) s2[j][f] = (v4f){0.f, 0.f, 0.f, 0.f};
#pragma unroll
      for (int f = 0; f < 4; ++f) {
        int row = f * 16 + lr;
        int sw = (row & 7) << 4;
#pragma unroll
        for (int c = 0; c < 4; ++c) {
          v8bf kf = *(const v8bf*)((const char*)lK + row * 256 + ((c * 64 + lg * 16) ^ sw));
          s2[0][f] = MFMA16(kf, qf[0][c], s2[0][f]);
          s2[1][f] = MFMA16(kf, qf[1][c], s2[1][f]);
        }
      }

      v8bf pa[2][2];
#pragma unroll
      for (int j = 0; j < 2; ++j) {
        int qg = q0 + j * 16 + lr;
        bool needMask = (kv0 + 63 > q0 + j * 16);
        float p[16];
        float mt = -1e30f;
#pragma unroll
        for (int f = 0; f < 4; ++f)
#pragma unroll
          for (int r = 0; r < 4; ++r) {
            float v = s2[j][f][r] * SCALE2;
            if (needMask && (kv0 + f * 16 + lg * 4 + r > qg)) v = -1e30f;
            p[f * 4 + r] = v;
            mt = fmaxf(mt, v);
          }
        mt = fmaxf(mt, __shfl_xor(mt, 16));
        mt = fmaxf(mt, __shfl_xor(mt, 32));
        if (!__all(mt <= mrow[j] + 8.0f)) {      // rescale (rare after warmup)
          float mnew = fmaxf(mrow[j], mt);
          float corr = exp2f(mrow[j] - mnew);
          mrow[j] = mnew;
          lrow[j] *= corr;
          float cf[4];
#pragma unroll
          for (int r = 0; r < 4; ++r) cf[r] = __shfl(corr, lg * 4 + r);
#pragma unroll
          for (int c = 0; c < 8; ++c)
#pragma unroll
            for (int r = 0; r < 4; ++r) o[j][c][r] *= cf[r];
        }
        float psum = 0.f;
#pragma unroll
        for (int r = 0; r < 16; ++r) { p[r] = exp2f(p[r] - mrow[j]); psum += p[r]; }
        psum += __shfl_xor(psum, 16);
        psum += __shfl_xor(psum, 32);
        lrow[j] += psum;
#pragma unroll
        for (int f = 0; f < 4; ++f) {
          v4bf pv = {(__bf16)p[f * 4], (__bf16)p[f * 4 + 1],
                     (__bf16)p[f * 4 + 2], (__bf16)p[f * 4 + 3]};
          *(v4bf*)&plds[w][j * 16 + lr][f * 16 + lg * 4] = pv;
        }
        asm volatile("s_waitcnt lgkmcnt(0)" ::: "memory");
        pa[j][0] = *(const v8bf*)&plds[w][j * 16 + lr][lg * 8];
        pa[j][1] = *(const v8bf*)&plds[w][j * 16 + lr][32 + lg * 8];
      }

      // ---- PV ----
#pragma unroll
      for (int c = 0; c < 8; ++c) {
        int row = c * 16 + lr;
        int sw = (row & 7) << 4;
        v8bf vf0 = *(const v8bf*)((const char*)lV + row * 128 + ((lg * 16) ^ sw));
        v8bf vf1 = *(const v8bf*)((const char*)lV + row * 128 + ((64 + lg * 16) ^ sw));
        o[0][c] = MFMA16(pa[0][0], vf0, o[0][c]);
        o[0][c] = MFMA16(pa[0][1], vf1, o[0][c]);
        o[1][c] = MFMA16(pa[1][0], vf0, o[1][c]);
        o[1][c] = MFMA16(pa[1][1], vf1, o[1][c]);
      }
    }
  }

  size_t ybase = ((size_t)b * T_SEQ) * CDIM + (size_t)h * DHEAD;
#pragma unroll
  for (int j = 0; j < 2; ++j) {
    float lf[4];
#pragma unroll
    for (int r = 0; r < 4; ++r) lf[r] = __shfl(lrow[j], lg * 4 + r);
#pragma unroll
    for (int c = 0; c < 8; ++c) {
#pragma unroll
      for (int r = 0; r < 4; ++r) {
        int qq = q0 + j * 16 + lg * 4 + r;
        Y[ybase + (size_t)qq * CDIM + c * 16 + lr] = (__bf16)(o[j][c][r] / lf[r]);
      }
    }
  }
}

// ---------------- launch -----------------------------------------------------
extern "C" void kernel_launch(void* const* d_in, const int* in_sizes, int n_in,
                              void* d_out, int out_size, void* d_ws, size_t ws_size,
                              hipStream_t stream) {
  const float* x      = (const float*)d_in[0];
  const float* w_attn = (const float*)d_in[1];
  const float* b_attn = (const float*)d_in[2];
  const float* w_proj = (const float*)d_in[3];
  const float* b_proj = (const float*)d_in[4];
  float* out = (float*)d_out;

  char* ws = (char*)d_ws;
  __bf16* xbf  = (__bf16*)(ws);                 // 33,554,432 B; reused as Y
  __bf16* wabf = (__bf16*)(ws + 33554432);      // 25,165,824 B
  __bf16* wpbf = (__bf16*)(ws + 58720256);      //  8,388,608 B
  __bf16* Qb   = (__bf16*)(ws + 67108864);      // 33,554,432 B (BH,T,D)
  __bf16* Kb   = (__bf16*)(ws + 100663296);     // 33,554,432 B (BH,T,D)
  __bf16* Vt   = (__bf16*)(ws + 134217728);     // 33,554,432 B (BH,D,T)
  __bf16* Y    = xbf;

  (void)hipFuncSetAttribute((const void*)gemm_qkv8,
                            hipFuncAttributeMaxDynamicSharedMemorySize, 131072);
  (void)hipFuncSetAttribute((const void*)gemm_out8,
                            hipFuncAttributeMaxDynamicSharedMemorySize, 131072);

  cvt_f32_bf16<<<1024, 256, 0, stream>>>(x, xbf, 16777216);
  cvt_f32_bf16<<<1024, 256, 0, stream>>>(w_attn, wabf, 12582912);
  cvt_f32_bf16<<<512, 256, 0, stream>>>(w_proj, wpbf, 4194304);

  gemm_qkv8<<<dim3(32, 24), 512, 131072, stream>>>(xbf, wabf, b_attn, Qb, Kb, Vt);

  rope_kernel<<<1024, 256, 0, stream>>>(Qb, Kb);

  attn_fwd<<<512, 512, 0, stream>>>(Qb, Kb, Vt, Y);

  gemm_out8<<<dim3(32, 8), 512, 131072, stream>>>(Y, wpbf, b_proj, out);
}

// Round 9
// 539.046 us; speedup vs baseline: 1.5269x; 1.0312x over previous
//
#include <hip/hip_runtime.h>

// Problem constants: B=4, T=2048, C=2048, H=16, D=128
#define T_SEQ 2048
#define DHEAD 128
#define NHEAD 16
#define CDIM  2048
#define BATCH 4

typedef __bf16 v8bf __attribute__((ext_vector_type(8)));
typedef __bf16 v4bf __attribute__((ext_vector_type(4)));
typedef float  v4f  __attribute__((ext_vector_type(4)));

#define MFMA16(a,b,c) __builtin_amdgcn_mfma_f32_16x16x32_bf16(a,b,c,0,0,0)
#define GLDS16(g,l) __builtin_amdgcn_global_load_lds( \
    (__attribute__((address_space(1))) void*)(g), \
    (__attribute__((address_space(3))) void*)(l), 16, 0, 0)

// ---------------- f32 -> bf16 convert (vectorized, grid-stride) --------------
__global__ __launch_bounds__(256) void cvt_f32_bf16(const float* __restrict__ in,
                                                    __bf16* __restrict__ out, int n) {
  int i = blockIdx.x * 256 + threadIdx.x;
  int stride = gridDim.x * 256;
  for (int j = i; 4 * j < n; j += stride) {
    float4 v = *(const float4*)(in + (size_t)j * 4);
    v4bf o = {(__bf16)v.x, (__bf16)v.y, (__bf16)v.z, (__bf16)v.w};
    *(v4bf*)(out + (size_t)j * 4) = o;
  }
}

// =============== 256x256 8-phase GEMM core (m201 template, plain HIP) =======
#define LGKM0() { asm volatile("s_waitcnt lgkmcnt(0)" ::: "memory"); \
                  __builtin_amdgcn_sched_barrier(0); }
#define BARR()  { __builtin_amdgcn_s_barrier(); __builtin_amdgcn_sched_barrier(0); }

#define RDA(mm, kk) (*(const v8bf*)(bA + (wm16 + (mm)*32 + lr) * 128 + ((((kk)*64) + lgc) ^ swl)))
#define RDB(n, kk)  (*(const v8bf*)(bB + (wn64 + (n)*16 + lr) * 128 + ((((kk)*64) + lgc) ^ swl)))
#define MF(mm,n,kk) acc[mm][n] = MFMA16(af[(mm)&1][kk], bfr[n][kk], acc[mm][n]);

#define PH_MFMA(MM0, MM1) \
  BARR(); LGKM0(); \
  __builtin_amdgcn_s_setprio(1); \
  MF(MM0,0,0) MF(MM0,1,0) MF(MM0,2,0) MF(MM0,3,0) \
  MF(MM1,0,0) MF(MM1,1,0) MF(MM1,2,0) MF(MM1,3,0) \
  MF(MM0,0,1) MF(MM0,1,1) MF(MM0,2,1) MF(MM0,3,1) \
  MF(MM1,0,1) MF(MM1,1,1) MF(MM1,2,1) MF(MM1,3,1) \
  __builtin_amdgcn_s_setprio(0); \
  BARR();

#define STAGE_H(SRC, ks, hh, LBASE) { \
  GLDS16((SRC) + (size_t)((hh)*128)      * 2048 + (size_t)(ks)*64, lds + (LBASE) + dst0); \
  GLDS16((SRC) + (size_t)((hh)*128 + 64) * 2048 + (size_t)(ks)*64, lds + (LBASE) + 4096 + dst0); }

#define TILE(CB, ks1, ks2) { \
  const char* bA = (const char*)(lds + (CB)*32768); \
  const char* bB = bA + 32768; \
  v8bf bfr[4][2], af[2][2]; \
  af[0][0]=RDA(0,0); af[0][1]=RDA(0,1); af[1][0]=RDA(1,0); af[1][1]=RDA(1,1); \
  bfr[0][0]=RDB(0,0); bfr[0][1]=RDB(0,1); bfr[1][0]=RDB(1,0); bfr[1][1]=RDB(1,1); \
  bfr[2][0]=RDB(2,0); bfr[2][1]=RDB(2,1); bfr[3][0]=RDB(3,0); bfr[3][1]=RDB(3,1); \
  STAGE_H(Asrc, ks1, 1, ((CB)^1)*32768 + 8192); \
  PH_MFMA(0, 1) \
  af[0][0]=RDA(2,0); af[0][1]=RDA(2,1); af[1][0]=RDA(3,0); af[1][1]=RDA(3,1); \
  STAGE_H(Bsrc, ks2, 0, (CB)*32768 + 16384); \
  PH_MFMA(2, 3) \
  af[0][0]=RDA(4,0); af[0][1]=RDA(4,1); af[1][0]=RDA(5,0); af[1][1]=RDA(5,1); \
  STAGE_H(Asrc, ks2, 0, (CB)*32768); \
  PH_MFMA(4, 5) \
  af[0][0]=RDA(6,0); af[0][1]=RDA(6,1); af[1][0]=RDA(7,0); af[1][1]=RDA(7,1); \
  STAGE_H(Bsrc, ks2, 1, (CB)*32768 + 24576); \
  asm volatile("s_waitcnt vmcnt(6)" ::: "memory"); \
  PH_MFMA(6, 7) \
}

__device__ __forceinline__ void gemm256_core(
    const __bf16* __restrict__ A, const __bf16* __restrict__ Bm,
    int row0, int col0, __bf16* lds, v4f (&acc)[8][4],
    int wm16, int wn64, int lr, int lg) {
  int t = threadIdx.x;
  int wid = t >> 6;
  int lgc = lg * 16;
  int swl = (lr & 7) << 4;
#pragma unroll
  for (int mm = 0; mm < 8; ++mm)
#pragma unroll
    for (int n = 0; n < 4; ++n) acc[mm][n] = (v4f){0.f, 0.f, 0.f, 0.f};

  int srow = t >> 3;
  int scol = (((t & 7) ^ ((t >> 3) & 7)) << 3);
  const __bf16* Asrc = A  + (size_t)(row0 + srow) * 2048 + scol;
  const __bf16* Bsrc = Bm + (size_t)(col0 + srow) * 2048 + scol;
  int dst0 = wid << 9;

  STAGE_H(Asrc, 0, 0, 0);
  STAGE_H(Asrc, 0, 1, 8192);
  STAGE_H(Bsrc, 0, 0, 16384);
  STAGE_H(Bsrc, 0, 1, 24576);
  STAGE_H(Bsrc, 1, 0, 32768 + 16384);
  STAGE_H(Asrc, 1, 0, 32768);
  STAGE_H(Bsrc, 1, 1, 32768 + 24576);
  asm volatile("s_waitcnt vmcnt(6)" ::: "memory");
  BARR();

  for (int m = 0; m < 32; m += 2) {
    TILE(0, m + 1, (m + 2) & 31)
    TILE(1, (m + 2) & 31, (m + 3) & 31)
  }
  asm volatile("s_waitcnt vmcnt(0)" ::: "memory");
}

// GEMM1: qkv = x * w_attn^T + b_attn; scatter epilogue -> Q,K (BH,T,D), Vt (BH,D,T)
// r9: 1D grid + XCD-chunked mapping (bid%8 = XCD): each XCD owns a 4-row-tile
// band (A-band 4 MB = L2) swept across all 24 col-tiles.
__global__ __launch_bounds__(512, 2) void gemm_qkv8(
    const __bf16* __restrict__ A, const __bf16* __restrict__ Bm,
    const float* __restrict__ bias,
    __bf16* __restrict__ Qb, __bf16* __restrict__ Kb, __bf16* __restrict__ Vt) {
  extern __shared__ __bf16 lds[];
  int t = threadIdx.x, wid = t >> 6, l = t & 63;
  int lr = l & 15, lg = l >> 4;
  int wm16 = (wid >> 2) * 16, wn64 = (wid & 3) * 64;
  int bid = blockIdx.x;
  int xcd = bid & 7, idx = bid >> 3;            // 96 blocks per XCD
  int row0 = (xcd * 4 + idx / 24) * 256;
  int col0 = (idx % 24) * 256;
  v4f acc[8][4];
  gemm256_core(A, Bm, row0, col0, lds, acc, wm16, wn64, lr, lg);

  if (col0 >= 4096) {
    // ---- V blocks: LDS-transposed coalesced store to Vt (BH,D,T) ----
    int h0 = (col0 & 2047) >> 7;
    int bb = row0 >> 11;
    int t0 = row0 & 2047;
    int d_r = t >> 1, half = t & 1;
    int hh = h0 + (d_r >> 7), dd = d_r & 127;
#pragma unroll
    for (int mm = 0; mm < 8; ++mm) {
      __syncthreads();
#pragma unroll
      for (int n = 0; n < 4; ++n) {
        int d_loc = wn64 + n * 16 + lr;
        float bv = bias[col0 + d_loc];
        v4bf pv = {(__bf16)(acc[mm][n][0] + bv), (__bf16)(acc[mm][n][1] + bv),
                   (__bf16)(acc[mm][n][2] + bv), (__bf16)(acc[mm][n][3] + bv)};
        *(v4bf*)&lds[d_loc * 40 + wm16 + lg * 4] = pv;
      }
      __syncthreads();
      size_t vbase = ((size_t)((bb * NHEAD + hh) * DHEAD + dd)) * T_SEQ
                   + t0 + mm * 32 + half * 16;
      v8bf x0 = *(const v8bf*)&lds[d_r * 40 + half * 16];
      v8bf x1 = *(const v8bf*)&lds[d_r * 40 + half * 16 + 8];
      *(v8bf*)&Vt[vbase] = x0;
      *(v8bf*)&Vt[vbase + 8] = x1;
    }
    return;
  }
#pragma unroll
  for (int n = 0; n < 4; ++n) {
    int col = col0 + wn64 + n * 16 + lr;
    int tensor = col >> 11;
    int wc = col & 2047;
    int h = wc >> 7, d = wc & 127;
    float bv = bias[col];
#pragma unroll
    for (int mm = 0; mm < 8; ++mm) {
#pragma unroll
      for (int rr = 0; rr < 4; ++rr) {
        int mg = row0 + wm16 + mm * 32 + lg * 4 + rr;
        int b = mg >> 11, tt = mg & 2047;
        float v = acc[mm][n][rr] + bv;
        size_t bh = (size_t)(b * NHEAD + h);
        if (tensor == 0) Qb[(bh * T_SEQ + tt) * DHEAD + d] = (__bf16)v;
        else             Kb[(bh * T_SEQ + tt) * DHEAD + d] = (__bf16)v;
      }
    }
  }
}

// GEMM2: out = Y * w_proj^T + b_proj, fp32 row-major epilogue; XCD-chunked map.
__global__ __launch_bounds__(512, 2) void gemm_out8(
    const __bf16* __restrict__ A, const __bf16* __restrict__ Bm,
    const float* __restrict__ bias, float* __restrict__ C) {
  extern __shared__ __bf16 lds[];
  int t = threadIdx.x, wid = t >> 6, l = t & 63;
  int lr = l & 15, lg = l >> 4;
  int wm16 = (wid >> 2) * 16, wn64 = (wid & 3) * 64;
  int bid = blockIdx.x;
  int xcd = bid & 7, idx = bid >> 3;            // 32 blocks per XCD
  int row0 = (xcd * 4 + idx / 8) * 256;
  int col0 = (idx % 8) * 256;
  v4f acc[8][4];
  gemm256_core(A, Bm, row0, col0, lds, acc, wm16, wn64, lr, lg);
#pragma unroll
  for (int n = 0; n < 4; ++n) {
    int col = col0 + wn64 + n * 16 + lr;
    float bv = bias[col];
#pragma unroll
    for (int mm = 0; mm < 8; ++mm) {
#pragma unroll
      for (int rr = 0; rr < 4; ++rr) {
        int mg = row0 + wm16 + mm * 32 + lg * 4 + rr;
        C[(size_t)mg * CDIM + col] = acc[mm][n][rr] + bv;
      }
    }
  }
}

// ---------------- RoPE in-place on Q,K (BH,T,D) ------------------------------
__global__ __launch_bounds__(256) void rope_kernel(__bf16* __restrict__ Qb,
                                                   __bf16* __restrict__ Kb) {
  int idx = blockIdx.x * 256 + threadIdx.x;
  __bf16* base = (idx & 131072) ? Kb : Qb;
  int r = idx & 131071;
  int tt = r & (T_SEQ - 1);
  __bf16* p = base + (size_t)r * DHEAD;
  v8bf xv[16];
#pragma unroll
  for (int j = 0; j < 16; ++j) xv[j] = *(const v8bf*)&p[j * 8];
  v8bf ov[16];
#pragma unroll
  for (int j = 0; j < 64; ++j) {
    float invf = exp2f((float)j * (-13.287712379549449f / 64.f));
    float ang = (float)tt * invf;
    float c = cosf(ang), s = sinf(ang);
    float cps = c + s, cms = c - s;
    float xj   = (float)xv[j >> 3][j & 7];
    float xj64 = (float)xv[(j + 64) >> 3][j & 7];
    float x2j  = (float)xv[(2 * j) >> 3][(2 * j) & 7];
    float x2j1 = (float)xv[(2 * j + 1) >> 3][(2 * j + 1) & 7];
    ov[j >> 3][j & 7]        = (__bf16)(xj * cps - x2j1 * cms);
    ov[(j + 64) >> 3][j & 7] = (__bf16)(xj64 * cps + x2j * cms);
  }
#pragma unroll
  for (int j = 0; j < 16; ++j) *(v8bf*)&p[j * 8] = ov[j];
}

// ---------------- flash attention v5 -----------------------------------------
// 512 thr = 8 waves, 256 q-rows/block; complementary CU pairing (r8).
// r9 (T14): K/V tile t+1 loaded to REGISTERS while computing tile t; ds_write
// after the consumption barrier. Same LDS layout/bytes as the glds path
// (dest elem = i*4096 + w*512 + lane*8); removes the vmem-drain barrier stall.
__global__ __launch_bounds__(512, 2) void attn_fwd(
    const __bf16* __restrict__ Qb, const __bf16* __restrict__ Kb,
    const __bf16* __restrict__ Vt, __bf16* __restrict__ Y) {
  __shared__ __bf16 lK[64 * 128];       // 16 KB, [kv][d] swizzled
  __shared__ __bf16 lV[128 * 64];       // 16 KB, [d][kv] swizzled
  __shared__ __bf16 plds[8][32][72];    // 36 KB, per-wave P, padded rows
  int t = threadIdx.x, w = t >> 6, l = t & 63;
  int lr = l & 15, lg = l >> 4;
  int id = blockIdx.x;                        // 0..511
  int xcd = id & 7, s = id >> 3;
  int bh = xcd * 8 + (s & 7);
  int g = s >> 3;
  int k = (g < 4) ? (7 - g) : (g - 4);
  int qb = k * 256;
  int b = bh >> 4, h = bh & 15;
  int q0 = qb + w * 32;
  const __bf16* Qh = Qb + (size_t)bh * T_SEQ * DHEAD;
  const __bf16* Kh = Kb + (size_t)bh * T_SEQ * DHEAD;
  const __bf16* Vh = Vt + (size_t)bh * DHEAD * T_SEQ;

  v8bf qf[2][4];
#pragma unroll
  for (int j = 0; j < 2; ++j)
#pragma unroll
    for (int c = 0; c < 4; ++c)
      qf[j][c] = *(const v8bf*)&Qh[(size_t)(q0 + j * 16 + lr) * DHEAD + c * 32 + lg * 8];

  v4f o[2][8];
#pragma unroll
  for (int j = 0; j < 2; ++j)
#pragma unroll
    for (int c = 0; c < 8; ++c) o[j][c] = (v4f){0.f, 0.f, 0.f, 0.f};
  float mrow[2] = {-1e30f, -1e30f}, lrow[2] = {0.f, 0.f};
  const float SCALE2 = 0.12751743f;   // (1/sqrt(128)) * log2(e)

  int kRow = t >> 4;                                       // 0..31
  int kSrc = (((t & 15) * 16) ^ ((kRow & 7) << 4)) >> 1;
  int vRow = t >> 3;                                       // 0..63
  int vSrc = (((t & 7) * 16) ^ ((vRow & 7) << 4)) >> 1;
  __bf16* lKd0 = lK + w * 512 + l * 8;
  __bf16* lKd1 = lK + 4096 + w * 512 + l * 8;
  __bf16* lVd0 = lV + w * 512 + l * 8;
  __bf16* lVd1 = lV + 4096 + w * 512 + l * 8;

  // prologue: tile 0 -> regs
  v8bf kr0 = *(const v8bf*)&Kh[(size_t)(kRow) * DHEAD + kSrc];
  v8bf kr1 = *(const v8bf*)&Kh[(size_t)(32 + kRow) * DHEAD + kSrc];
  v8bf vr0 = *(const v8bf*)&Vh[(size_t)(vRow) * T_SEQ + vSrc];
  v8bf vr1 = *(const v8bf*)&Vh[(size_t)(64 + vRow) * T_SEQ + vSrc];

  int kvEnd = qb + 192;
  for (int kv0 = 0; kv0 <= kvEnd; kv0 += 64) {
    __syncthreads();                       // prior tile fully consumed
    *(v8bf*)lKd0 = kr0; *(v8bf*)lKd1 = kr1;
    *(v8bf*)lVd0 = vr0; *(v8bf*)lVd1 = vr1;
    __syncthreads();                       // tile visible
    if (kv0 + 64 <= kvEnd) {               // prefetch next tile (wave-uniform)
      kr0 = *(const v8bf*)&Kh[(size_t)(kv0 + 64 + kRow) * DHEAD + kSrc];
      kr1 = *(const v8bf*)&Kh[(size_t)(kv0 + 96 + kRow) * DHEAD + kSrc];
      vr0 = *(const v8bf*)&Vh[(size_t)(vRow) * T_SEQ + kv0 + 64 + vSrc];
      vr1 = *(const v8bf*)&Vh[(size_t)(64 + vRow) * T_SEQ + kv0 + 64 + vSrc];
    }

    if (kv0 <= q0 + 31) {
      // ---- QK^T (swapped): S[64 kv][32 q] ----
      v4f s2[2][4];
#pragma unroll
      for (int j = 0; j < 2; ++j)
#pragma unroll
        for (int f = 0; f < 4; ++f) s2[j][f] = (v4f){0.f, 0.f, 0.f, 0.f};
#pragma unroll
      for (int f = 0; f < 4; ++f) {
        int row = f * 16 + lr;
        int sw = (row & 7) << 4;
#pragma unroll
        for (int c = 0; c < 4; ++c) {
          v8bf kf = *(const v8bf*)((const char*)lK + row * 256 + ((c * 64 + lg * 16) ^ sw));
          s2[0][f] = MFMA16(kf, qf[0][c], s2[0][f]);
          s2[1][f] = MFMA16(kf, qf[1][c], s2[1][f]);
        }
      }

      v8bf pa[2][2];
#pragma unroll
      for (int j = 0; j < 2; ++j) {
        int qg = q0 + j * 16 + lr;
        bool needMask = (kv0 + 63 > q0 + j * 16);
        float p[16];
        float mt = -1e30f;
#pragma unroll
        for (int f = 0; f < 4; ++f)
#pragma unroll
          for (int r = 0; r < 4; ++r) {
            float v = s2[j][f][r] * SCALE2;
            if (needMask && (kv0 + f * 16 + lg * 4 + r > qg)) v = -1e30f;
            p[f * 4 + r] = v;
            mt = fmaxf(mt, v);
          }
        mt = fmaxf(mt, __shfl_xor(mt, 16));
        mt = fmaxf(mt, __shfl_xor(mt, 32));
        if (!__all(mt <= mrow[j] + 8.0f)) {      // rescale (rare after warmup)
          float mnew = fmaxf(mrow[j], mt);
          float corr = exp2f(mrow[j] - mnew);
          mrow[j] = mnew;
          lrow[j] *= corr;
          float cf[4];
#pragma unroll
          for (int r = 0; r < 4; ++r) cf[r] = __shfl(corr, lg * 4 + r);
#pragma unroll
          for (int c = 0; c < 8; ++c)
#pragma unroll
            for (int r = 0; r < 4; ++r) o[j][c][r] *= cf[r];
        }
        float psum = 0.f;
#pragma unroll
        for (int r = 0; r < 16; ++r) { p[r] = exp2f(p[r] - mrow[j]); psum += p[r]; }
        psum += __shfl_xor(psum, 16);
        psum += __shfl_xor(psum, 32);
        lrow[j] += psum;
#pragma unroll
        for (int f = 0; f < 4; ++f) {
          v4bf pv = {(__bf16)p[f * 4], (__bf16)p[f * 4 + 1],
                     (__bf16)p[f * 4 + 2], (__bf16)p[f * 4 + 3]};
          *(v4bf*)&plds[w][j * 16 + lr][f * 16 + lg * 4] = pv;
        }
        asm volatile("s_waitcnt lgkmcnt(0)" ::: "memory");
        pa[j][0] = *(const v8bf*)&plds[w][j * 16 + lr][lg * 8];
        pa[j][1] = *(const v8bf*)&plds[w][j * 16 + lr][32 + lg * 8];
      }

      // ---- PV ----
#pragma unroll
      for (int c = 0; c < 8; ++c) {
        int row = c * 16 + lr;
        int sw = (row & 7) << 4;
        v8bf vf0 = *(const v8bf*)((const char*)lV + row * 128 + ((lg * 16) ^ sw));
        v8bf vf1 = *(const v8bf*)((const char*)lV + row * 128 + ((64 + lg * 16) ^ sw));
        o[0][c] = MFMA16(pa[0][0], vf0, o[0][c]);
        o[0][c] = MFMA16(pa[0][1], vf1, o[0][c]);
        o[1][c] = MFMA16(pa[1][0], vf0, o[1][c]);
        o[1][c] = MFMA16(pa[1][1], vf1, o[1][c]);
      }
    }
  }

  size_t ybase = ((size_t)b * T_SEQ) * CDIM + (size_t)h * DHEAD;
#pragma unroll
  for (int j = 0; j < 2; ++j) {
    float lf[4];
#pragma unroll
    for (int r = 0; r < 4; ++r) lf[r] = __shfl(lrow[j], lg * 4 + r);
#pragma unroll
    for (int c = 0; c < 8; ++c) {
#pragma unroll
      for (int r = 0; r < 4; ++r) {
        int qq = q0 + j * 16 + lg * 4 + r;
        Y[ybase + (size_t)qq * CDIM + c * 16 + lr] = (__bf16)(o[j][c][r] / lf[r]);
      }
    }
  }
}

// ---------------- launch -----------------------------------------------------
extern "C" void kernel_launch(void* const* d_in, const int* in_sizes, int n_in,
                              void* d_out, int out_size, void* d_ws, size_t ws_size,
                              hipStream_t stream) {
  const float* x      = (const float*)d_in[0];
  const float* w_attn = (const float*)d_in[1];
  const float* b_attn = (const float*)d_in[2];
  const float* w_proj = (const float*)d_in[3];
  const float* b_proj = (const float*)d_in[4];
  float* out = (float*)d_out;

  char* ws = (char*)d_ws;
  __bf16* xbf  = (__bf16*)(ws);                 // 33,554,432 B; reused as Y
  __bf16* wabf = (__bf16*)(ws + 33554432);      // 25,165,824 B
  __bf16* wpbf = (__bf16*)(ws + 58720256);      //  8,388,608 B
  __bf16* Qb   = (__bf16*)(ws + 67108864);      // 33,554,432 B (BH,T,D)
  __bf16* Kb   = (__bf16*)(ws + 100663296);     // 33,554,432 B (BH,T,D)
  __bf16* Vt   = (__bf16*)(ws + 134217728);     // 33,554,432 B (BH,D,T)
  __bf16* Y    = xbf;

  (void)hipFuncSetAttribute((const void*)gemm_qkv8,
                            hipFuncAttributeMaxDynamicSharedMemorySize, 131072);
  (void)hipFuncSetAttribute((const void*)gemm_out8,
                            hipFuncAttributeMaxDynamicSharedMemorySize, 131072);

  cvt_f32_bf16<<<1024, 256, 0, stream>>>(x, xbf, 16777216);
  cvt_f32_bf16<<<1024, 256, 0, stream>>>(w_attn, wabf, 12582912);
  cvt_f32_bf16<<<512, 256, 0, stream>>>(w_proj, wpbf, 4194304);

  gemm_qkv8<<<768, 512, 131072, stream>>>(xbf, wabf, b_attn, Qb, Kb, Vt);

  rope_kernel<<<1024, 256, 0, stream>>>(Qb, Kb);

  attn_fwd<<<512, 512, 0, stream>>>(Qb, Kb, Vt, Y);

  gemm_out8<<<256, 512, 131072, stream>>>(Y, wpbf, b_proj, out);
}

// Round 10
// 516.563 us; speedup vs baseline: 1.5934x; 1.0435x over previous
//
#include <hip/hip_runtime.h>

// Problem constants: B=4, T=2048, C=2048, H=16, D=128
#define T_SEQ 2048
#define DHEAD 128
#define NHEAD 16
#define CDIM  2048
#define BATCH 4

typedef __bf16 v8bf __attribute__((ext_vector_type(8)));
typedef __bf16 v4bf __attribute__((ext_vector_type(4)));
typedef float  v4f  __attribute__((ext_vector_type(4)));

#define MFMA16(a,b,c) __builtin_amdgcn_mfma_f32_16x16x32_bf16(a,b,c,0,0,0)
#define GLDS16(g,l) __builtin_amdgcn_global_load_lds( \
    (__attribute__((address_space(1))) void*)(g), \
    (__attribute__((address_space(3))) void*)(l), 16, 0, 0)

// ---------------- fused f32 -> bf16 convert (x, w_attn, w_proj) --------------
__global__ __launch_bounds__(256) void cvt_all(const float* __restrict__ x,
                                               const float* __restrict__ wa,
                                               const float* __restrict__ wp,
                                               __bf16* __restrict__ xo,
                                               __bf16* __restrict__ wao,
                                               __bf16* __restrict__ wpo) {
  int i = blockIdx.x * 256 + threadIdx.x;
  int stride = gridDim.x * 256;
  for (int j = i; j < 8388608; j += stride) {   // total float4s
    const float* src; __bf16* dst; int off;
    if (j < 4194304)      { src = x;  dst = xo;  off = j; }
    else if (j < 7340032) { src = wa; dst = wao; off = j - 4194304; }
    else                  { src = wp; dst = wpo; off = j - 7340032; }
    float4 v = *(const float4*)(src + (size_t)off * 4);
    v4bf o = {(__bf16)v.x, (__bf16)v.y, (__bf16)v.z, (__bf16)v.w};
    *(v4bf*)(dst + (size_t)off * 4) = o;
  }
}

// =============== 256x256 8-phase GEMM core (m201 template, plain HIP) =======
#define LGKM0() { asm volatile("s_waitcnt lgkmcnt(0)" ::: "memory"); \
                  __builtin_amdgcn_sched_barrier(0); }
#define BARR()  { __builtin_amdgcn_s_barrier(); __builtin_amdgcn_sched_barrier(0); }

#define RDA(mm, kk) (*(const v8bf*)(bA + (wm16 + (mm)*32 + lr) * 128 + ((((kk)*64) + lgc) ^ swl)))
#define RDB(n, kk)  (*(const v8bf*)(bB + (wn64 + (n)*16 + lr) * 128 + ((((kk)*64) + lgc) ^ swl)))
#define MF(mm,n,kk) acc[mm][n] = MFMA16(af[(mm)&1][kk], bfr[n][kk], acc[mm][n]);

#define PH_MFMA(MM0, MM1) \
  BARR(); LGKM0(); \
  __builtin_amdgcn_s_setprio(1); \
  MF(MM0,0,0) MF(MM0,1,0) MF(MM0,2,0) MF(MM0,3,0) \
  MF(MM1,0,0) MF(MM1,1,0) MF(MM1,2,0) MF(MM1,3,0) \
  MF(MM0,0,1) MF(MM0,1,1) MF(MM0,2,1) MF(MM0,3,1) \
  MF(MM1,0,1) MF(MM1,1,1) MF(MM1,2,1) MF(MM1,3,1) \
  __builtin_amdgcn_s_setprio(0); \
  BARR();

#define STAGE_H(SRC, ks, hh, LBASE) { \
  GLDS16((SRC) + (size_t)((hh)*128)      * 2048 + (size_t)(ks)*64, lds + (LBASE) + dst0); \
  GLDS16((SRC) + (size_t)((hh)*128 + 64) * 2048 + (size_t)(ks)*64, lds + (LBASE) + 4096 + dst0); }

#define TILE(CB, ks1, ks2) { \
  const char* bA = (const char*)(lds + (CB)*32768); \
  const char* bB = bA + 32768; \
  v8bf bfr[4][2], af[2][2]; \
  af[0][0]=RDA(0,0); af[0][1]=RDA(0,1); af[1][0]=RDA(1,0); af[1][1]=RDA(1,1); \
  bfr[0][0]=RDB(0,0); bfr[0][1]=RDB(0,1); bfr[1][0]=RDB(1,0); bfr[1][1]=RDB(1,1); \
  bfr[2][0]=RDB(2,0); bfr[2][1]=RDB(2,1); bfr[3][0]=RDB(3,0); bfr[3][1]=RDB(3,1); \
  STAGE_H(Asrc, ks1, 1, ((CB)^1)*32768 + 8192); \
  PH_MFMA(0, 1) \
  af[0][0]=RDA(2,0); af[0][1]=RDA(2,1); af[1][0]=RDA(3,0); af[1][1]=RDA(3,1); \
  STAGE_H(Bsrc, ks2, 0, (CB)*32768 + 16384); \
  PH_MFMA(2, 3) \
  af[0][0]=RDA(4,0); af[0][1]=RDA(4,1); af[1][0]=RDA(5,0); af[1][1]=RDA(5,1); \
  STAGE_H(Asrc, ks2, 0, (CB)*32768); \
  PH_MFMA(4, 5) \
  af[0][0]=RDA(6,0); af[0][1]=RDA(6,1); af[1][0]=RDA(7,0); af[1][1]=RDA(7,1); \
  STAGE_H(Bsrc, ks2, 1, (CB)*32768 + 24576); \
  asm volatile("s_waitcnt vmcnt(6)" ::: "memory"); \
  PH_MFMA(6, 7) \
}

__device__ __forceinline__ void gemm256_core(
    const __bf16* __restrict__ A, const __bf16* __restrict__ Bm,
    int row0, int col0, __bf16* lds, v4f (&acc)[8][4],
    int wm16, int wn64, int lr, int lg) {
  int t = threadIdx.x;
  int wid = t >> 6;
  int lgc = lg * 16;
  int swl = (lr & 7) << 4;
#pragma unroll
  for (int mm = 0; mm < 8; ++mm)
#pragma unroll
    for (int n = 0; n < 4; ++n) acc[mm][n] = (v4f){0.f, 0.f, 0.f, 0.f};

  int srow = t >> 3;
  int scol = (((t & 7) ^ ((t >> 3) & 7)) << 3);
  const __bf16* Asrc = A  + (size_t)(row0 + srow) * 2048 + scol;
  const __bf16* Bsrc = Bm + (size_t)(col0 + srow) * 2048 + scol;
  int dst0 = wid << 9;

  STAGE_H(Asrc, 0, 0, 0);
  STAGE_H(Asrc, 0, 1, 8192);
  STAGE_H(Bsrc, 0, 0, 16384);
  STAGE_H(Bsrc, 0, 1, 24576);
  STAGE_H(Bsrc, 1, 0, 32768 + 16384);
  STAGE_H(Asrc, 1, 0, 32768);
  STAGE_H(Bsrc, 1, 1, 32768 + 24576);
  asm volatile("s_waitcnt vmcnt(6)" ::: "memory");
  BARR();

  for (int m = 0; m < 32; m += 2) {
    TILE(0, m + 1, (m + 2) & 31)
    TILE(1, (m + 2) & 31, (m + 3) & 31)
  }
  asm volatile("s_waitcnt vmcnt(0)" ::: "memory");
}

// GEMM1: qkv = x * w_attn^T + b_attn.
// Q/K blocks: fused bias+RoPE epilogue via 128-KB LDS tile (r10): stage acc
// to swizzled LDS, one thread per (head,row) applies RoPE and streams the row.
// V blocks: LDS-transposed coalesced store to Vt (BH,D,T).
__global__ __launch_bounds__(512, 2) void gemm_qkv8(
    const __bf16* __restrict__ A, const __bf16* __restrict__ Bm,
    const float* __restrict__ bias,
    __bf16* __restrict__ Qb, __bf16* __restrict__ Kb, __bf16* __restrict__ Vt) {
  extern __shared__ __bf16 lds[];
  int t = threadIdx.x, wid = t >> 6, l = t & 63;
  int lr = l & 15, lg = l >> 4;
  int wm16 = (wid >> 2) * 16, wn64 = (wid & 3) * 64;
  int bid = blockIdx.x;
  int xcd = bid & 7, idx = bid >> 3;            // 96 blocks per XCD
  int row0 = (xcd * 4 + idx / 24) * 256;
  int col0 = (idx % 24) * 256;
  v4f acc[8][4];
  gemm256_core(A, Bm, row0, col0, lds, acc, wm16, wn64, lr, lg);

  if (col0 >= 4096) {
    // ---- V blocks ----
    int h0 = (col0 & 2047) >> 7;
    int bb = row0 >> 11;
    int t0 = row0 & 2047;
    int d_r = t >> 1, half = t & 1;
    int hh = h0 + (d_r >> 7), dd = d_r & 127;
#pragma unroll
    for (int mm = 0; mm < 8; ++mm) {
      __syncthreads();   // first: all waves past vmcnt(0); later: prev reads done
#pragma unroll
      for (int n = 0; n < 4; ++n) {
        int d_loc = wn64 + n * 16 + lr;
        float bv = bias[col0 + d_loc];
        v4bf pv = {(__bf16)(acc[mm][n][0] + bv), (__bf16)(acc[mm][n][1] + bv),
                   (__bf16)(acc[mm][n][2] + bv), (__bf16)(acc[mm][n][3] + bv)};
        *(v4bf*)&lds[d_loc * 40 + wm16 + lg * 4] = pv;
      }
      __syncthreads();
      size_t vbase = ((size_t)((bb * NHEAD + hh) * DHEAD + dd)) * T_SEQ
                   + t0 + mm * 32 + half * 16;
      v8bf x0 = *(const v8bf*)&lds[d_r * 40 + half * 16];
      v8bf x1 = *(const v8bf*)&lds[d_r * 40 + half * 16 + 8];
      *(v8bf*)&Vt[vbase] = x0;
      *(v8bf*)&Vt[vbase + 8] = x1;
    }
    return;
  }

  // ---- Q/K blocks: fused bias + RoPE ----
  __syncthreads();   // ALL waves past vmcnt(0): stale tail glds landed in lds
  // stage acc+bias -> swizzled LDS tile [256 rows][512 B]; byte (2c)^((r&31)<<4)
#pragma unroll
  for (int n = 0; n < 4; ++n) {
    int c_loc = wn64 + n * 16 + lr;
    float bv = bias[col0 + c_loc];
#pragma unroll
    for (int mm = 0; mm < 8; ++mm) {
#pragma unroll
      for (int rr = 0; rr < 4; ++rr) {
        int r_loc = wm16 + mm * 32 + lg * 4 + rr;
        *(__bf16*)((char*)lds + r_loc * 512 + ((2 * c_loc) ^ ((r_loc & 31) << 4)))
            = (__bf16)(acc[mm][n][rr] + bv);
      }
    }
  }
  __syncthreads();
  {
    int u = t >> 8, r = t & 255;                 // head-half, row
    int tensor = col0 >> 11;                     // 0=Q, 1=K
    int h = ((col0 & 2047) >> 7) + u;
    int mg = row0 + r;
    int b = mg >> 11, tt = mg & 2047;
    const char* lrow_ = (const char*)lds + r * 512;
    int swz = (r & 31) << 4;
    v8bf xv[16];
#pragma unroll
    for (int i = 0; i < 16; ++i)
      xv[i] = *(const v8bf*)(lrow_ + ((u * 256 + i * 16) ^ swz));
    v8bf ov[16];
#pragma unroll
    for (int j = 0; j < 64; ++j) {
      float invf = exp2f((float)j * (-13.287712379549449f / 64.f));  // 10000^(-j/64)
      float ang = (float)tt * invf;
      float c = cosf(ang), s = sinf(ang);
      float cps = c + s, cms = c - s;
      float xj   = (float)xv[j >> 3][j & 7];
      float xj64 = (float)xv[(j + 64) >> 3][j & 7];
      float x2j  = (float)xv[(2 * j) >> 3][(2 * j) & 7];
      float x2j1 = (float)xv[(2 * j + 1) >> 3][(2 * j + 1) & 7];
      ov[j >> 3][j & 7]        = (__bf16)(xj * cps - x2j1 * cms);
      ov[(j + 64) >> 3][j & 7] = (__bf16)(xj64 * cps + x2j * cms);
    }
    __bf16* dst = (tensor ? Kb : Qb)
                + ((size_t)(b * NHEAD + h) * T_SEQ + tt) * DHEAD;
#pragma unroll
    for (int i = 0; i < 16; ++i) *(v8bf*)(dst + i * 8) = ov[i];
  }
}

// GEMM2: out = Y * w_proj^T + b_proj, fp32 row-major epilogue; XCD-chunked map.
__global__ __launch_bounds__(512, 2) void gemm_out8(
    const __bf16* __restrict__ A, const __bf16* __restrict__ Bm,
    const float* __restrict__ bias, float* __restrict__ C) {
  extern __shared__ __bf16 lds[];
  int t = threadIdx.x, wid = t >> 6, l = t & 63;
  int lr = l & 15, lg = l >> 4;
  int wm16 = (wid >> 2) * 16, wn64 = (wid & 3) * 64;
  int bid = blockIdx.x;
  int xcd = bid & 7, idx = bid >> 3;            // 32 blocks per XCD
  int row0 = (xcd * 4 + idx / 8) * 256;
  int col0 = (idx % 8) * 256;
  v4f acc[8][4];
  gemm256_core(A, Bm, row0, col0, lds, acc, wm16, wn64, lr, lg);
#pragma unroll
  for (int n = 0; n < 4; ++n) {
    int col = col0 + wn64 + n * 16 + lr;
    float bv = bias[col];
#pragma unroll
    for (int mm = 0; mm < 8; ++mm) {
#pragma unroll
      for (int rr = 0; rr < 4; ++rr) {
        int mg = row0 + wm16 + mm * 32 + lg * 4 + rr;
        C[(size_t)mg * CDIM + col] = acc[mm][n][rr] + bv;
      }
    }
  }
}

// ---------------- flash attention v5 -----------------------------------------
// 512 thr = 8 waves, 256 q-rows/block; complementary CU pairing (r8);
// T14 reg-prefetch of next K/V tile (r9).
__global__ __launch_bounds__(512, 2) void attn_fwd(
    const __bf16* __restrict__ Qb, const __bf16* __restrict__ Kb,
    const __bf16* __restrict__ Vt, __bf16* __restrict__ Y) {
  __shared__ __bf16 lK[64 * 128];       // 16 KB, [kv][d] swizzled
  __shared__ __bf16 lV[128 * 64];       // 16 KB, [d][kv] swizzled
  __shared__ __bf16 plds[8][32][72];    // 36 KB, per-wave P, padded rows
  int t = threadIdx.x, w = t >> 6, l = t & 63;
  int lr = l & 15, lg = l >> 4;
  int id = blockIdx.x;                        // 0..511
  int xcd = id & 7, s = id >> 3;
  int bh = xcd * 8 + (s & 7);
  int g = s >> 3;
  int k = (g < 4) ? (7 - g) : (g - 4);
  int qb = k * 256;
  int b = bh >> 4, h = bh & 15;
  int q0 = qb + w * 32;
  const __bf16* Qh = Qb + (size_t)bh * T_SEQ * DHEAD;
  const __bf16* Kh = Kb + (size_t)bh * T_SEQ * DHEAD;
  const __bf16* Vh = Vt + (size_t)bh * DHEAD * T_SEQ;

  v8bf qf[2][4];
#pragma unroll
  for (int j = 0; j < 2; ++j)
#pragma unroll
    for (int c = 0; c < 4; ++c)
      qf[j][c] = *(const v8bf*)&Qh[(size_t)(q0 + j * 16 + lr) * DHEAD + c * 32 + lg * 8];

  v4f o[2][8];
#pragma unroll
  for (int j = 0; j < 2; ++j)
#pragma unroll
    for (int c = 0; c < 8; ++c) o[j][c] = (v4f){0.f, 0.f, 0.f, 0.f};
  float mrow[2] = {-1e30f, -1e30f}, lrow[2] = {0.f, 0.f};
  const float SCALE2 = 0.12751743f;   // (1/sqrt(128)) * log2(e)

  int kRow = t >> 4;                                       // 0..31
  int kSrc = (((t & 15) * 16) ^ ((kRow & 7) << 4)) >> 1;
  int vRow = t >> 3;                                       // 0..63
  int vSrc = (((t & 7) * 16) ^ ((vRow & 7) << 4)) >> 1;
  __bf16* lKd0 = lK + w * 512 + l * 8;
  __bf16* lKd1 = lK + 4096 + w * 512 + l * 8;
  __bf16* lVd0 = lV + w * 512 + l * 8;
  __bf16* lVd1 = lV + 4096 + w * 512 + l * 8;

  // prologue: tile 0 -> regs
  v8bf kr0 = *(const v8bf*)&Kh[(size_t)(kRow) * DHEAD + kSrc];
  v8bf kr1 = *(const v8bf*)&Kh[(size_t)(32 + kRow) * DHEAD + kSrc];
  v8bf vr0 = *(const v8bf*)&Vh[(size_t)(vRow) * T_SEQ + vSrc];
  v8bf vr1 = *(const v8bf*)&Vh[(size_t)(64 + vRow) * T_SEQ + vSrc];

  int kvEnd = qb + 192;
  for (int kv0 = 0; kv0 <= kvEnd; kv0 += 64) {
    __syncthreads();                       // prior tile fully consumed
    *(v8bf*)lKd0 = kr0; *(v8bf*)lKd1 = kr1;
    *(v8bf*)lVd0 = vr0; *(v8bf*)lVd1 = vr1;
    __syncthreads();                       // tile visible
    if (kv0 + 64 <= kvEnd) {               // prefetch next tile (wave-uniform)
      kr0 = *(const v8bf*)&Kh[(size_t)(kv0 + 64 + kRow) * DHEAD + kSrc];
      kr1 = *(const v8bf*)&Kh[(size_t)(kv0 + 96 + kRow) * DHEAD + kSrc];
      vr0 = *(const v8bf*)&Vh[(size_t)(vRow) * T_SEQ + kv0 + 64 + vSrc];
      vr1 = *(const v8bf*)&Vh[(size_t)(64 + vRow) * T_SEQ + kv0 + 64 + vSrc];
    }

    if (kv0 <= q0 + 31) {
      // ---- QK^T (swapped): S[64 kv][32 q] ----
      v4f s2[2][4];
#pragma unroll
      for (int j = 0; j < 2; ++j)
#pragma unroll
        for (int f = 0; f < 4; ++f) s2[j][f] = (v4f){0.f, 0.f, 0.f, 0.f};
#pragma unroll
      for (int f = 0; f < 4; ++f) {
        int row = f * 16 + lr;
        int sw = (row & 7) << 4;
#pragma unroll
        for (int c = 0; c < 4; ++c) {
          v8bf kf = *(const v8bf*)((const char*)lK + row * 256 + ((c * 64 + lg * 16) ^ sw));
          s2[0][f] = MFMA16(kf, qf[0][c], s2[0][f]);
          s2[1][f] = MFMA16(kf, qf[1][c], s2[1][f]);
        }
      }

      v8bf pa[2][2];
#pragma unroll
      for (int j = 0; j < 2; ++j) {
        int qg = q0 + j * 16 + lr;
        bool needMask = (kv0 + 63 > q0 + j * 16);
        float p[16];
        float mt = -1e30f;
#pragma unroll
        for (int f = 0; f < 4; ++f)
#pragma unroll
          for (int r = 0; r < 4; ++r) {
            float v = s2[j][f][r] * SCALE2;
            if (needMask && (kv0 + f * 16 + lg * 4 + r > qg)) v = -1e30f;
            p[f * 4 + r] = v;
            mt = fmaxf(mt, v);
          }
        mt = fmaxf(mt, __shfl_xor(mt, 16));
        mt = fmaxf(mt, __shfl_xor(mt, 32));
        if (!__all(mt <= mrow[j] + 8.0f)) {      // rescale (rare after warmup)
          float mnew = fmaxf(mrow[j], mt);
          float corr = exp2f(mrow[j] - mnew);
          mrow[j] = mnew;
          lrow[j] *= corr;
          float cf[4];
#pragma unroll
          for (int r = 0; r < 4; ++r) cf[r] = __shfl(corr, lg * 4 + r);
#pragma unroll
          for (int c = 0; c < 8; ++c)
#pragma unroll
            for (int r = 0; r < 4; ++r) o[j][c][r] *= cf[r];
        }
        float psum = 0.f;
#pragma unroll
        for (int r = 0; r < 16; ++r) { p[r] = exp2f(p[r] - mrow[j]); psum += p[r]; }
        psum += __shfl_xor(psum, 16);
        psum += __shfl_xor(psum, 32);
        lrow[j] += psum;
#pragma unroll
        for (int f = 0; f < 4; ++f) {
          v4bf pv = {(__bf16)p[f * 4], (__bf16)p[f * 4 + 1],
                     (__bf16)p[f * 4 + 2], (__bf16)p[f * 4 + 3]};
          *(v4bf*)&plds[w][j * 16 + lr][f * 16 + lg * 4] = pv;
        }
        asm volatile("s_waitcnt lgkmcnt(0)" ::: "memory");
        pa[j][0] = *(const v8bf*)&plds[w][j * 16 + lr][lg * 8];
        pa[j][1] = *(const v8bf*)&plds[w][j * 16 + lr][32 + lg * 8];
      }

      // ---- PV ----
#pragma unroll
      for (int c = 0; c < 8; ++c) {
        int row = c * 16 + lr;
        int sw = (row & 7) << 4;
        v8bf vf0 = *(const v8bf*)((const char*)lV + row * 128 + ((lg * 16) ^ sw));
        v8bf vf1 = *(const v8bf*)((const char*)lV + row * 128 + ((64 + lg * 16) ^ sw));
        o[0][c] = MFMA16(pa[0][0], vf0, o[0][c]);
        o[0][c] = MFMA16(pa[0][1], vf1, o[0][c]);
        o[1][c] = MFMA16(pa[1][0], vf0, o[1][c]);
        o[1][c] = MFMA16(pa[1][1], vf1, o[1][c]);
      }
    }
  }

  size_t ybase = ((size_t)b * T_SEQ) * CDIM + (size_t)h * DHEAD;
#pragma unroll
  for (int j = 0; j < 2; ++j) {
    float lf[4];
#pragma unroll
    for (int r = 0; r < 4; ++r) lf[r] = __shfl(lrow[j], lg * 4 + r);
#pragma unroll
    for (int c = 0; c < 8; ++c) {
#pragma unroll
      for (int r = 0; r < 4; ++r) {
        int qq = q0 + j * 16 + lg * 4 + r;
        Y[ybase + (size_t)qq * CDIM + c * 16 + lr] = (__bf16)(o[j][c][r] / lf[r]);
      }
    }
  }
}

// ---------------- launch -----------------------------------------------------
extern "C" void kernel_launch(void* const* d_in, const int* in_sizes, int n_in,
                              void* d_out, int out_size, void* d_ws, size_t ws_size,
                              hipStream_t stream) {
  const float* x      = (const float*)d_in[0];
  const float* w_attn = (const float*)d_in[1];
  const float* b_attn = (const float*)d_in[2];
  const float* w_proj = (const float*)d_in[3];
  const float* b_proj = (const float*)d_in[4];
  float* out = (float*)d_out;

  char* ws = (char*)d_ws;
  __bf16* xbf  = (__bf16*)(ws);                 // 33,554,432 B; reused as Y
  __bf16* wabf = (__bf16*)(ws + 33554432);      // 25,165,824 B
  __bf16* wpbf = (__bf16*)(ws + 58720256);      //  8,388,608 B
  __bf16* Qb   = (__bf16*)(ws + 67108864);      // 33,554,432 B (BH,T,D)
  __bf16* Kb   = (__bf16*)(ws + 100663296);     // 33,554,432 B (BH,T,D)
  __bf16* Vt   = (__bf16*)(ws + 134217728);     // 33,554,432 B (BH,D,T)
  __bf16* Y    = xbf;

  (void)hipFuncSetAttribute((const void*)gemm_qkv8,
                            hipFuncAttributeMaxDynamicSharedMemorySize, 131072);
  (void)hipFuncSetAttribute((const void*)gemm_out8,
                            hipFuncAttributeMaxDynamicSharedMemorySize, 131072);

  cvt_all<<<2048, 256, 0, stream>>>(x, w_attn, w_proj, xbf, wabf, wpbf);

  gemm_qkv8<<<768, 512, 131072, stream>>>(xbf, wabf, b_attn, Qb, Kb, Vt);

  attn_fwd<<<512, 512, 0, stream>>>(Qb, Kb, Vt, Y);

  gemm_out8<<<256, 512, 131072, stream>>>(Y, wpbf, b_proj, out);
}

// Round 11
// 485.024 us; speedup vs baseline: 1.6970x; 1.0650x over previous
//
#include <hip/hip_runtime.h>

// Problem constants: B=4, T=2048, C=2048, H=16, D=128
#define T_SEQ 2048
#define DHEAD 128
#define NHEAD 16
#define CDIM  2048
#define BATCH 4

typedef __bf16 v8bf __attribute__((ext_vector_type(8)));
typedef __bf16 v4bf __attribute__((ext_vector_type(4)));
typedef float  v4f  __attribute__((ext_vector_type(4)));

#define MFMA16(a,b,c) __builtin_amdgcn_mfma_f32_16x16x32_bf16(a,b,c,0,0,0)
#define GLDS16(g,l) __builtin_amdgcn_global_load_lds( \
    (__attribute__((address_space(1))) void*)(g), \
    (__attribute__((address_space(3))) void*)(l), 16, 0, 0)

// ------- fused f32 -> bf16 convert (x, w_attn, w_proj) + RoPE table ---------
// r11: table tab[tt][j] = {cos+sin, cos-sin} (f32), same formulas as the old
// in-epilogue trig -> numerically identical; 1 MB, L2-resident afterwards.
__global__ __launch_bounds__(256) void cvt_all(const float* __restrict__ x,
                                               const float* __restrict__ wa,
                                               const float* __restrict__ wp,
                                               __bf16* __restrict__ xo,
                                               __bf16* __restrict__ wao,
                                               __bf16* __restrict__ wpo,
                                               float2* __restrict__ rt) {
  int i = blockIdx.x * 256 + threadIdx.x;
  int stride = gridDim.x * 256;
  for (int j = i; j < 8519680; j += stride) {   // 8388608 float4s + 131072 tab
    if (j < 8388608) {
      const float* src; __bf16* dst; int off;
      if (j < 4194304)      { src = x;  dst = xo;  off = j; }
      else if (j < 7340032) { src = wa; dst = wao; off = j - 4194304; }
      else                  { src = wp; dst = wpo; off = j - 7340032; }
      float4 v = *(const float4*)(src + (size_t)off * 4);
      v4bf o = {(__bf16)v.x, (__bf16)v.y, (__bf16)v.z, (__bf16)v.w};
      *(v4bf*)(dst + (size_t)off * 4) = o;
    } else {
      int e = j - 8388608;                     // 0..131071
      int tt = e >> 6, jj = e & 63;
      float invf = exp2f((float)jj * (-13.287712379549449f / 64.f));
      float ang = (float)tt * invf;
      float c = cosf(ang), s = sinf(ang);
      rt[e] = make_float2(c + s, c - s);
    }
  }
}

// =============== 256x256 8-phase GEMM core (m201 template, plain HIP) =======
#define LGKM0() { asm volatile("s_waitcnt lgkmcnt(0)" ::: "memory"); \
                  __builtin_amdgcn_sched_barrier(0); }
#define BARR()  { __builtin_amdgcn_s_barrier(); __builtin_amdgcn_sched_barrier(0); }

#define RDA(mm, kk) (*(const v8bf*)(bA + (wm16 + (mm)*32 + lr) * 128 + ((((kk)*64) + lgc) ^ swl)))
#define RDB(n, kk)  (*(const v8bf*)(bB + (wn64 + (n)*16 + lr) * 128 + ((((kk)*64) + lgc) ^ swl)))
#define MF(mm,n,kk) acc[mm][n] = MFMA16(af[(mm)&1][kk], bfr[n][kk], acc[mm][n]);

#define PH_MFMA(MM0, MM1) \
  BARR(); LGKM0(); \
  __builtin_amdgcn_s_setprio(1); \
  MF(MM0,0,0) MF(MM0,1,0) MF(MM0,2,0) MF(MM0,3,0) \
  MF(MM1,0,0) MF(MM1,1,0) MF(MM1,2,0) MF(MM1,3,0) \
  MF(MM0,0,1) MF(MM0,1,1) MF(MM0,2,1) MF(MM0,3,1) \
  MF(MM1,0,1) MF(MM1,1,1) MF(MM1,2,1) MF(MM1,3,1) \
  __builtin_amdgcn_s_setprio(0); \
  BARR();

#define STAGE_H(SRC, ks, hh, LBASE) { \
  GLDS16((SRC) + (size_t)((hh)*128)      * 2048 + (size_t)(ks)*64, lds + (LBASE) + dst0); \
  GLDS16((SRC) + (size_t)((hh)*128 + 64) * 2048 + (size_t)(ks)*64, lds + (LBASE) + 4096 + dst0); }

#define TILE(CB, ks1, ks2) { \
  const char* bA = (const char*)(lds + (CB)*32768); \
  const char* bB = bA + 32768; \
  v8bf bfr[4][2], af[2][2]; \
  af[0][0]=RDA(0,0); af[0][1]=RDA(0,1); af[1][0]=RDA(1,0); af[1][1]=RDA(1,1); \
  bfr[0][0]=RDB(0,0); bfr[0][1]=RDB(0,1); bfr[1][0]=RDB(1,0); bfr[1][1]=RDB(1,1); \
  bfr[2][0]=RDB(2,0); bfr[2][1]=RDB(2,1); bfr[3][0]=RDB(3,0); bfr[3][1]=RDB(3,1); \
  STAGE_H(Asrc, ks1, 1, ((CB)^1)*32768 + 8192); \
  PH_MFMA(0, 1) \
  af[0][0]=RDA(2,0); af[0][1]=RDA(2,1); af[1][0]=RDA(3,0); af[1][1]=RDA(3,1); \
  STAGE_H(Bsrc, ks2, 0, (CB)*32768 + 16384); \
  PH_MFMA(2, 3) \
  af[0][0]=RDA(4,0); af[0][1]=RDA(4,1); af[1][0]=RDA(5,0); af[1][1]=RDA(5,1); \
  STAGE_H(Asrc, ks2, 0, (CB)*32768); \
  PH_MFMA(4, 5) \
  af[0][0]=RDA(6,0); af[0][1]=RDA(6,1); af[1][0]=RDA(7,0); af[1][1]=RDA(7,1); \
  STAGE_H(Bsrc, ks2, 1, (CB)*32768 + 24576); \
  asm volatile("s_waitcnt vmcnt(6)" ::: "memory"); \
  PH_MFMA(6, 7) \
}

__device__ __forceinline__ void gemm256_core(
    const __bf16* __restrict__ A, const __bf16* __restrict__ Bm,
    int row0, int col0, __bf16* lds, v4f (&acc)[8][4],
    int wm16, int wn64, int lr, int lg) {
  int t = threadIdx.x;
  int wid = t >> 6;
  int lgc = lg * 16;
  int swl = (lr & 7) << 4;
#pragma unroll
  for (int mm = 0; mm < 8; ++mm)
#pragma unroll
    for (int n = 0; n < 4; ++n) acc[mm][n] = (v4f){0.f, 0.f, 0.f, 0.f};

  int srow = t >> 3;
  int scol = (((t & 7) ^ ((t >> 3) & 7)) << 3);
  const __bf16* Asrc = A  + (size_t)(row0 + srow) * 2048 + scol;
  const __bf16* Bsrc = Bm + (size_t)(col0 + srow) * 2048 + scol;
  int dst0 = wid << 9;

  STAGE_H(Asrc, 0, 0, 0);
  STAGE_H(Asrc, 0, 1, 8192);
  STAGE_H(Bsrc, 0, 0, 16384);
  STAGE_H(Bsrc, 0, 1, 24576);
  STAGE_H(Bsrc, 1, 0, 32768 + 16384);
  STAGE_H(Asrc, 1, 0, 32768);
  STAGE_H(Bsrc, 1, 1, 32768 + 24576);
  asm volatile("s_waitcnt vmcnt(6)" ::: "memory");
  BARR();

  for (int m = 0; m < 32; m += 2) {
    TILE(0, m + 1, (m + 2) & 31)
    TILE(1, (m + 2) & 31, (m + 3) & 31)
  }
  asm volatile("s_waitcnt vmcnt(0)" ::: "memory");
}

// GEMM1: qkv = x * w_attn^T + b_attn.
// Q/K blocks: fused bias+RoPE epilogue (table-driven, r11) via 128-KB LDS tile.
// V blocks: LDS-transposed coalesced store to Vt (BH,D,T).
__global__ __launch_bounds__(512, 2) void gemm_qkv8(
    const __bf16* __restrict__ A, const __bf16* __restrict__ Bm,
    const float* __restrict__ bias, const float2* __restrict__ rt,
    __bf16* __restrict__ Qb, __bf16* __restrict__ Kb, __bf16* __restrict__ Vt) {
  extern __shared__ __bf16 lds[];
  int t = threadIdx.x, wid = t >> 6, l = t & 63;
  int lr = l & 15, lg = l >> 4;
  int wm16 = (wid >> 2) * 16, wn64 = (wid & 3) * 64;
  int bid = blockIdx.x;
  int xcd = bid & 7, idx = bid >> 3;            // 96 blocks per XCD
  int row0 = (xcd * 4 + idx / 24) * 256;
  int col0 = (idx % 24) * 256;
  v4f acc[8][4];
  gemm256_core(A, Bm, row0, col0, lds, acc, wm16, wn64, lr, lg);

  if (col0 >= 4096) {
    // ---- V blocks ----
    int h0 = (col0 & 2047) >> 7;
    int bb = row0 >> 11;
    int t0 = row0 & 2047;
    int d_r = t >> 1, half = t & 1;
    int hh = h0 + (d_r >> 7), dd = d_r & 127;
#pragma unroll
    for (int mm = 0; mm < 8; ++mm) {
      __syncthreads();   // first: all waves past vmcnt(0); later: prev reads done
#pragma unroll
      for (int n = 0; n < 4; ++n) {
        int d_loc = wn64 + n * 16 + lr;
        float bv = bias[col0 + d_loc];
        v4bf pv = {(__bf16)(acc[mm][n][0] + bv), (__bf16)(acc[mm][n][1] + bv),
                   (__bf16)(acc[mm][n][2] + bv), (__bf16)(acc[mm][n][3] + bv)};
        *(v4bf*)&lds[d_loc * 40 + wm16 + lg * 4] = pv;
      }
      __syncthreads();
      size_t vbase = ((size_t)((bb * NHEAD + hh) * DHEAD + dd)) * T_SEQ
                   + t0 + mm * 32 + half * 16;
      v8bf x0 = *(const v8bf*)&lds[d_r * 40 + half * 16];
      v8bf x1 = *(const v8bf*)&lds[d_r * 40 + half * 16 + 8];
      *(v8bf*)&Vt[vbase] = x0;
      *(v8bf*)&Vt[vbase + 8] = x1;
    }
    return;
  }

  // ---- Q/K blocks: fused bias + RoPE (table) ----
  __syncthreads();   // ALL waves past vmcnt(0): stale tail glds landed in lds
#pragma unroll
  for (int n = 0; n < 4; ++n) {
    int c_loc = wn64 + n * 16 + lr;
    float bv = bias[col0 + c_loc];
#pragma unroll
    for (int mm = 0; mm < 8; ++mm) {
#pragma unroll
      for (int rr = 0; rr < 4; ++rr) {
        int r_loc = wm16 + mm * 32 + lg * 4 + rr;
        *(__bf16*)((char*)lds + r_loc * 512 + ((2 * c_loc) ^ ((r_loc & 31) << 4)))
            = (__bf16)(acc[mm][n][rr] + bv);
      }
    }
  }
  __syncthreads();
  {
    int u = t >> 8, r = t & 255;                 // head-half, row
    int tensor = col0 >> 11;                     // 0=Q, 1=K
    int h = ((col0 & 2047) >> 7) + u;
    int mg = row0 + r;
    int b = mg >> 11, tt = mg & 2047;
    const char* lrow_ = (const char*)lds + r * 512;
    int swz = (r & 31) << 4;
    v8bf xv[16];
#pragma unroll
    for (int i = 0; i < 16; ++i)
      xv[i] = *(const v8bf*)(lrow_ + ((u * 256 + i * 16) ^ swz));
    const float2* tb = rt + (size_t)tt * 64;
    v8bf ov[16];
#pragma unroll
    for (int j = 0; j < 64; ++j) {
      float2 cc = tb[j];                         // {cos+sin, cos-sin}
      float xj   = (float)xv[j >> 3][j & 7];
      float xj64 = (float)xv[(j + 64) >> 3][j & 7];
      float x2j  = (float)xv[(2 * j) >> 3][(2 * j) & 7];
      float x2j1 = (float)xv[(2 * j + 1) >> 3][(2 * j + 1) & 7];
      ov[j >> 3][j & 7]        = (__bf16)(xj * cc.x - x2j1 * cc.y);
      ov[(j + 64) >> 3][j & 7] = (__bf16)(xj64 * cc.x + x2j * cc.y);
    }
    __bf16* dst = (tensor ? Kb : Qb)
                + ((size_t)(b * NHEAD + h) * T_SEQ + tt) * DHEAD;
#pragma unroll
    for (int i = 0; i < 16; ++i) *(v8bf*)(dst + i * 8) = ov[i];
  }
}

// GEMM2: out = Y * w_proj^T + b_proj, fp32 row-major epilogue; XCD-chunked map.
__global__ __launch_bounds__(512, 2) void gemm_out8(
    const __bf16* __restrict__ A, const __bf16* __restrict__ Bm,
    const float* __restrict__ bias, float* __restrict__ C) {
  extern __shared__ __bf16 lds[];
  int t = threadIdx.x, wid = t >> 6, l = t & 63;
  int lr = l & 15, lg = l >> 4;
  int wm16 = (wid >> 2) * 16, wn64 = (wid & 3) * 64;
  int bid = blockIdx.x;
  int xcd = bid & 7, idx = bid >> 3;            // 32 blocks per XCD
  int row0 = (xcd * 4 + idx / 8) * 256;
  int col0 = (idx % 8) * 256;
  v4f acc[8][4];
  gemm256_core(A, Bm, row0, col0, lds, acc, wm16, wn64, lr, lg);
#pragma unroll
  for (int n = 0; n < 4; ++n) {
    int col = col0 + wn64 + n * 16 + lr;
    float bv = bias[col];
#pragma unroll
    for (int mm = 0; mm < 8; ++mm) {
#pragma unroll
      for (int rr = 0; rr < 4; ++rr) {
        int mg = row0 + wm16 + mm * 32 + lg * 4 + rr;
        C[(size_t)mg * CDIM + col] = acc[mm][n][rr] + bv;
      }
    }
  }
}

// ---------------- flash attention v5 -----------------------------------------
// 512 thr = 8 waves, 256 q-rows/block; complementary CU pairing (r8);
// T14 reg-prefetch of next K/V tile (r9).
__global__ __launch_bounds__(512, 2) void attn_fwd(
    const __bf16* __restrict__ Qb, const __bf16* __restrict__ Kb,
    const __bf16* __restrict__ Vt, __bf16* __restrict__ Y) {
  __shared__ __bf16 lK[64 * 128];       // 16 KB, [kv][d] swizzled
  __shared__ __bf16 lV[128 * 64];       // 16 KB, [d][kv] swizzled
  __shared__ __bf16 plds[8][32][72];    // 36 KB, per-wave P, padded rows
  int t = threadIdx.x, w = t >> 6, l = t & 63;
  int lr = l & 15, lg = l >> 4;
  int id = blockIdx.x;                        // 0..511
  int xcd = id & 7, s = id >> 3;
  int bh = xcd * 8 + (s & 7);
  int g = s >> 3;
  int k = (g < 4) ? (7 - g) : (g - 4);
  int qb = k * 256;
  int b = bh >> 4, h = bh & 15;
  int q0 = qb + w * 32;
  const __bf16* Qh = Qb + (size_t)bh * T_SEQ * DHEAD;
  const __bf16* Kh = Kb + (size_t)bh * T_SEQ * DHEAD;
  const __bf16* Vh = Vt + (size_t)bh * DHEAD * T_SEQ;

  v8bf qf[2][4];
#pragma unroll
  for (int j = 0; j < 2; ++j)
#pragma unroll
    for (int c = 0; c < 4; ++c)
      qf[j][c] = *(const v8bf*)&Qh[(size_t)(q0 + j * 16 + lr) * DHEAD + c * 32 + lg * 8];

  v4f o[2][8];
#pragma unroll
  for (int j = 0; j < 2; ++j)
#pragma unroll
    for (int c = 0; c < 8; ++c) o[j][c] = (v4f){0.f, 0.f, 0.f, 0.f};
  float mrow[2] = {-1e30f, -1e30f}, lrow[2] = {0.f, 0.f};
  const float SCALE2 = 0.12751743f;   // (1/sqrt(128)) * log2(e)

  int kRow = t >> 4;                                       // 0..31
  int kSrc = (((t & 15) * 16) ^ ((kRow & 7) << 4)) >> 1;
  int vRow = t >> 3;                                       // 0..63
  int vSrc = (((t & 7) * 16) ^ ((vRow & 7) << 4)) >> 1;
  __bf16* lKd0 = lK + w * 512 + l * 8;
  __bf16* lKd1 = lK + 4096 + w * 512 + l * 8;
  __bf16* lVd0 = lV + w * 512 + l * 8;
  __bf16* lVd1 = lV + 4096 + w * 512 + l * 8;

  // prologue: tile 0 -> regs
  v8bf kr0 = *(const v8bf*)&Kh[(size_t)(kRow) * DHEAD + kSrc];
  v8bf kr1 = *(const v8bf*)&Kh[(size_t)(32 + kRow) * DHEAD + kSrc];
  v8bf vr0 = *(const v8bf*)&Vh[(size_t)(vRow) * T_SEQ + vSrc];
  v8bf vr1 = *(const v8bf*)&Vh[(size_t)(64 + vRow) * T_SEQ + vSrc];

  int kvEnd = qb + 192;
  for (int kv0 = 0; kv0 <= kvEnd; kv0 += 64) {
    __syncthreads();                       // prior tile fully consumed
    *(v8bf*)lKd0 = kr0; *(v8bf*)lKd1 = kr1;
    *(v8bf*)lVd0 = vr0; *(v8bf*)lVd1 = vr1;
    __syncthreads();                       // tile visible
    if (kv0 + 64 <= kvEnd) {               // prefetch next tile (wave-uniform)
      kr0 = *(const v8bf*)&Kh[(size_t)(kv0 + 64 + kRow) * DHEAD + kSrc];
      kr1 = *(const v8bf*)&Kh[(size_t)(kv0 + 96 + kRow) * DHEAD + kSrc];
      vr0 = *(const v8bf*)&Vh[(size_t)(vRow) * T_SEQ + kv0 + 64 + vSrc];
      vr1 = *(const v8bf*)&Vh[(size_t)(64 + vRow) * T_SEQ + kv0 + 64 + vSrc];
    }

    if (kv0 <= q0 + 31) {
      // ---- QK^T (swapped): S[64 kv][32 q] ----
      v4f s2[2][4];
#pragma unroll
      for (int j = 0; j < 2; ++j)
#pragma unroll
        for (int f = 0; f < 4; ++f) s2[j][f] = (v4f){0.f, 0.f, 0.f, 0.f};
#pragma unroll
      for (int f = 0; f < 4; ++f) {
        int row = f * 16 + lr;
        int sw = (row & 7) << 4;
#pragma unroll
        for (int c = 0; c < 4; ++c) {
          v8bf kf = *(const v8bf*)((const char*)lK + row * 256 + ((c * 64 + lg * 16) ^ sw));
          s2[0][f] = MFMA16(kf, qf[0][c], s2[0][f]);
          s2[1][f] = MFMA16(kf, qf[1][c], s2[1][f]);
        }
      }

      v8bf pa[2][2];
#pragma unroll
      for (int j = 0; j < 2; ++j) {
        int qg = q0 + j * 16 + lr;
        bool needMask = (kv0 + 63 > q0 + j * 16);
        float p[16];
        float mt = -1e30f;
#pragma unroll
        for (int f = 0; f < 4; ++f)
#pragma unroll
          for (int r = 0; r < 4; ++r) {
            float v = s2[j][f][r] * SCALE2;
            if (needMask && (kv0 + f * 16 + lg * 4 + r > qg)) v = -1e30f;
            p[f * 4 + r] = v;
            mt = fmaxf(mt, v);
          }
        mt = fmaxf(mt, __shfl_xor(mt, 16));
        mt = fmaxf(mt, __shfl_xor(mt, 32));
        if (!__all(mt <= mrow[j] + 8.0f)) {      // rescale (rare after warmup)
          float mnew = fmaxf(mrow[j], mt);
          float corr = exp2f(mrow[j] - mnew);
          mrow[j] = mnew;
          lrow[j] *= corr;
          float cf[4];
#pragma unroll
          for (int r = 0; r < 4; ++r) cf[r] = __shfl(corr, lg * 4 + r);
#pragma unroll
          for (int c = 0; c < 8; ++c)
#pragma unroll
            for (int r = 0; r < 4; ++r) o[j][c][r] *= cf[r];
        }
        float psum = 0.f;
#pragma unroll
        for (int r = 0; r < 16; ++r) { p[r] = exp2f(p[r] - mrow[j]); psum += p[r]; }
        psum += __shfl_xor(psum, 16);
        psum += __shfl_xor(psum, 32);
        lrow[j] += psum;
#pragma unroll
        for (int f = 0; f < 4; ++f) {
          v4bf pv = {(__bf16)p[f * 4], (__bf16)p[f * 4 + 1],
                     (__bf16)p[f * 4 + 2], (__bf16)p[f * 4 + 3]};
          *(v4bf*)&plds[w][j * 16 + lr][f * 16 + lg * 4] = pv;
        }
        asm volatile("s_waitcnt lgkmcnt(0)" ::: "memory");
        pa[j][0] = *(const v8bf*)&plds[w][j * 16 + lr][lg * 8];
        pa[j][1] = *(const v8bf*)&plds[w][j * 16 + lr][32 + lg * 8];
      }

      // ---- PV ----
#pragma unroll
      for (int c = 0; c < 8; ++c) {
        int row = c * 16 + lr;
        int sw = (row & 7) << 4;
        v8bf vf0 = *(const v8bf*)((const char*)lV + row * 128 + ((lg * 16) ^ sw));
        v8bf vf1 = *(const v8bf*)((const char*)lV + row * 128 + ((64 + lg * 16) ^ sw));
        o[0][c] = MFMA16(pa[0][0], vf0, o[0][c]);
        o[0][c] = MFMA16(pa[0][1], vf1, o[0][c]);
        o[1][c] = MFMA16(pa[1][0], vf0, o[1][c]);
        o[1][c] = MFMA16(pa[1][1], vf1, o[1][c]);
      }
    }
  }

  size_t ybase = ((size_t)b * T_SEQ) * CDIM + (size_t)h * DHEAD;
#pragma unroll
  for (int j = 0; j < 2; ++j) {
    float lf[4];
#pragma unroll
    for (int r = 0; r < 4; ++r) lf[r] = __shfl(lrow[j], lg * 4 + r);
#pragma unroll
    for (int c = 0; c < 8; ++c) {
#pragma unroll
      for (int r = 0; r < 4; ++r) {
        int qq = q0 + j * 16 + lg * 4 + r;
        Y[ybase + (size_t)qq * CDIM + c * 16 + lr] = (__bf16)(o[j][c][r] / lf[r]);
      }
    }
  }
}

// ---------------- launch -----------------------------------------------------
extern "C" void kernel_launch(void* const* d_in, const int* in_sizes, int n_in,
                              void* d_out, int out_size, void* d_ws, size_t ws_size,
                              hipStream_t stream) {
  const float* x      = (const float*)d_in[0];
  const float* w_attn = (const float*)d_in[1];
  const float* b_attn = (const float*)d_in[2];
  const float* w_proj = (const float*)d_in[3];
  const float* b_proj = (const float*)d_in[4];
  float* out = (float*)d_out;

  char* ws = (char*)d_ws;
  __bf16* xbf  = (__bf16*)(ws);                 // 33,554,432 B; reused as Y
  __bf16* wabf = (__bf16*)(ws + 33554432);      // 25,165,824 B
  __bf16* wpbf = (__bf16*)(ws + 58720256);      //  8,388,608 B
  __bf16* Qb   = (__bf16*)(ws + 67108864);      // 33,554,432 B (BH,T,D)
  __bf16* Kb   = (__bf16*)(ws + 100663296);     // 33,554,432 B (BH,T,D)
  __bf16* Vt   = (__bf16*)(ws + 134217728);     // 33,554,432 B (BH,D,T)
  float2* rtab = (float2*)(ws + 167772160);     //  1,048,576 B rope table
  __bf16* Y    = xbf;

  (void)hipFuncSetAttribute((const void*)gemm_qkv8,
                            hipFuncAttributeMaxDynamicSharedMemorySize, 131072);
  (void)hipFuncSetAttribute((const void*)gemm_out8,
                            hipFuncAttributeMaxDynamicSharedMemorySize, 131072);

  cvt_all<<<2048, 256, 0, stream>>>(x, w_attn, w_proj, xbf, wabf, wpbf, rtab);

  gemm_qkv8<<<768, 512, 131072, stream>>>(xbf, wabf, b_attn, rtab, Qb, Kb, Vt);

  attn_fwd<<<512, 512, 0, stream>>>(Qb, Kb, Vt, Y);

  gemm_out8<<<256, 512, 131072, stream>>>(Y, wpbf, b_proj, out);
}

// Round 12
// 428.127 us; speedup vs baseline: 1.9225x; 1.1329x over previous
//
#include <hip/hip_runtime.h>

// Problem constants: B=4, T=2048, C=2048, H=16, D=128
#define T_SEQ 2048
#define DHEAD 128
#define NHEAD 16
#define CDIM  2048
#define BATCH 4

typedef __bf16 v8bf __attribute__((ext_vector_type(8)));
typedef __bf16 v4bf __attribute__((ext_vector_type(4)));
typedef __bf16 v2bf __attribute__((ext_vector_type(2)));
typedef float  v4f  __attribute__((ext_vector_type(4)));

#define MFMA16(a,b,c) __builtin_amdgcn_mfma_f32_16x16x32_bf16(a,b,c,0,0,0)
#define GLDS16(g,l) __builtin_amdgcn_global_load_lds( \
    (__attribute__((address_space(1))) void*)(g), \
    (__attribute__((address_space(3))) void*)(l), 16, 0, 0)

// ------- fused f32 -> bf16 convert (x, w_attn, w_proj) + RoPE table ---------
__global__ __launch_bounds__(256) void cvt_all(const float* __restrict__ x,
                                               const float* __restrict__ wa,
                                               const float* __restrict__ wp,
                                               __bf16* __restrict__ xo,
                                               __bf16* __restrict__ wao,
                                               __bf16* __restrict__ wpo,
                                               float2* __restrict__ rt) {
  int i = blockIdx.x * 256 + threadIdx.x;
  int stride = gridDim.x * 256;
  for (int j = i; j < 8519680; j += stride) {   // 8388608 float4s + 131072 tab
    if (j < 8388608) {
      const float* src; __bf16* dst; int off;
      if (j < 4194304)      { src = x;  dst = xo;  off = j; }
      else if (j < 7340032) { src = wa; dst = wao; off = j - 4194304; }
      else                  { src = wp; dst = wpo; off = j - 7340032; }
      float4 v = *(const float4*)(src + (size_t)off * 4);
      v4bf o = {(__bf16)v.x, (__bf16)v.y, (__bf16)v.z, (__bf16)v.w};
      *(v4bf*)(dst + (size_t)off * 4) = o;
    } else {
      int e = j - 8388608;                     // 0..131071
      int tt = e >> 6, jj = e & 63;
      float invf = exp2f((float)jj * (-13.287712379549449f / 64.f));
      float ang = (float)tt * invf;
      float c = cosf(ang), s = sinf(ang);
      rt[e] = make_float2(c + s, c - s);
    }
  }
}

// =============== 256x256 8-phase GEMM core (m201 template, plain HIP) =======
#define LGKM0() { asm volatile("s_waitcnt lgkmcnt(0)" ::: "memory"); \
                  __builtin_amdgcn_sched_barrier(0); }
#define BARR()  { __builtin_amdgcn_s_barrier(); __builtin_amdgcn_sched_barrier(0); }

#define RDA(mm, kk) (*(const v8bf*)(bA + (wm16 + (mm)*32 + lr) * 128 + ((((kk)*64) + lgc) ^ swl)))
#define RDB(n, kk)  (*(const v8bf*)(bB + (wn64 + (n)*16 + lr) * 128 + ((((kk)*64) + lgc) ^ swl)))
#define MF(mm,n,kk) acc[mm][n] = MFMA16(af[(mm)&1][kk], bfr[n][kk], acc[mm][n]);

#define PH_MFMA(MM0, MM1) \
  BARR(); LGKM0(); \
  __builtin_amdgcn_s_setprio(1); \
  MF(MM0,0,0) MF(MM0,1,0) MF(MM0,2,0) MF(MM0,3,0) \
  MF(MM1,0,0) MF(MM1,1,0) MF(MM1,2,0) MF(MM1,3,0) \
  MF(MM0,0,1) MF(MM0,1,1) MF(MM0,2,1) MF(MM0,3,1) \
  MF(MM1,0,1) MF(MM1,1,1) MF(MM1,2,1) MF(MM1,3,1) \
  __builtin_amdgcn_s_setprio(0); \
  BARR();

#define STAGE_H(SRC, ks, hh, LBASE) { \
  GLDS16((SRC) + (size_t)((hh)*128)      * 2048 + (size_t)(ks)*64, lds + (LBASE) + dst0); \
  GLDS16((SRC) + (size_t)((hh)*128 + 64) * 2048 + (size_t)(ks)*64, lds + (LBASE) + 4096 + dst0); }

#define TILE(CB, ks1, ks2) { \
  const char* bA = (const char*)(lds + (CB)*32768); \
  const char* bB = bA + 32768; \
  v8bf bfr[4][2], af[2][2]; \
  af[0][0]=RDA(0,0); af[0][1]=RDA(0,1); af[1][0]=RDA(1,0); af[1][1]=RDA(1,1); \
  bfr[0][0]=RDB(0,0); bfr[0][1]=RDB(0,1); bfr[1][0]=RDB(1,0); bfr[1][1]=RDB(1,1); \
  bfr[2][0]=RDB(2,0); bfr[2][1]=RDB(2,1); bfr[3][0]=RDB(3,0); bfr[3][1]=RDB(3,1); \
  STAGE_H(Asrc, ks1, 1, ((CB)^1)*32768 + 8192); \
  PH_MFMA(0, 1) \
  af[0][0]=RDA(2,0); af[0][1]=RDA(2,1); af[1][0]=RDA(3,0); af[1][1]=RDA(3,1); \
  STAGE_H(Bsrc, ks2, 0, (CB)*32768 + 16384); \
  PH_MFMA(2, 3) \
  af[0][0]=RDA(4,0); af[0][1]=RDA(4,1); af[1][0]=RDA(5,0); af[1][1]=RDA(5,1); \
  STAGE_H(Asrc, ks2, 0, (CB)*32768); \
  PH_MFMA(4, 5) \
  af[0][0]=RDA(6,0); af[0][1]=RDA(6,1); af[1][0]=RDA(7,0); af[1][1]=RDA(7,1); \
  STAGE_H(Bsrc, ks2, 1, (CB)*32768 + 24576); \
  asm volatile("s_waitcnt vmcnt(6)" ::: "memory"); \
  PH_MFMA(6, 7) \
}

__device__ __forceinline__ void gemm256_core(
    const __bf16* __restrict__ A, const __bf16* __restrict__ Bm,
    int row0, int col0, __bf16* lds, v4f (&acc)[8][4],
    int wm16, int wn64, int lr, int lg) {
  int t = threadIdx.x;
  int wid = t >> 6;
  int lgc = lg * 16;
  int swl = (lr & 7) << 4;
#pragma unroll
  for (int mm = 0; mm < 8; ++mm)
#pragma unroll
    for (int n = 0; n < 4; ++n) acc[mm][n] = (v4f){0.f, 0.f, 0.f, 0.f};

  int srow = t >> 3;
  int scol = (((t & 7) ^ ((t >> 3) & 7)) << 3);
  const __bf16* Asrc = A  + (size_t)(row0 + srow) * 2048 + scol;
  const __bf16* Bsrc = Bm + (size_t)(col0 + srow) * 2048 + scol;
  int dst0 = wid << 9;

  STAGE_H(Asrc, 0, 0, 0);
  STAGE_H(Asrc, 0, 1, 8192);
  STAGE_H(Bsrc, 0, 0, 16384);
  STAGE_H(Bsrc, 0, 1, 24576);
  STAGE_H(Bsrc, 1, 0, 32768 + 16384);
  STAGE_H(Asrc, 1, 0, 32768);
  STAGE_H(Bsrc, 1, 1, 32768 + 24576);
  asm volatile("s_waitcnt vmcnt(6)" ::: "memory");
  BARR();

  for (int m = 0; m < 32; m += 2) {
    TILE(0, m + 1, (m + 2) & 31)
    TILE(1, (m + 2) & 31, (m + 3) & 31)
  }
  asm volatile("s_waitcnt vmcnt(0)" ::: "memory");
}

// GEMM1: qkv = x * w_attn^T + b_attn.
// Q/K: fused bias+RoPE epilogue. r12: lane = column-pair, loop = rows.
// Removes r11's xv[16]/ov[16] register arrays (VGPR cap hit -> spill) and
// makes table loads wave-contiguous (r11: lane = row -> 64-line gather).
// V: LDS-transposed coalesced store to Vt (BH,D,T).
__global__ __launch_bounds__(512, 2) void gemm_qkv8(
    const __bf16* __restrict__ A, const __bf16* __restrict__ Bm,
    const float* __restrict__ bias, const float2* __restrict__ rt,
    __bf16* __restrict__ Qb, __bf16* __restrict__ Kb, __bf16* __restrict__ Vt) {
  extern __shared__ __bf16 lds[];
  int t = threadIdx.x, wid = t >> 6, l = t & 63;
  int lr = l & 15, lg = l >> 4;
  int wm16 = (wid >> 2) * 16, wn64 = (wid & 3) * 64;
  int bid = blockIdx.x;
  int xcd = bid & 7, idx = bid >> 3;            // 96 blocks per XCD
  int row0 = (xcd * 4 + idx / 24) * 256;
  int col0 = (idx % 24) * 256;
  v4f acc[8][4];
  gemm256_core(A, Bm, row0, col0, lds, acc, wm16, wn64, lr, lg);

  if (col0 >= 4096) {
    // ---- V blocks ----
    int h0 = (col0 & 2047) >> 7;
    int bb = row0 >> 11;
    int t0 = row0 & 2047;
    int d_r = t >> 1, half = t & 1;
    int hh = h0 + (d_r >> 7), dd = d_r & 127;
#pragma unroll
    for (int mm = 0; mm < 8; ++mm) {
      __syncthreads();   // first: all waves past vmcnt(0); later: prev reads done
#pragma unroll
      for (int n = 0; n < 4; ++n) {
        int d_loc = wn64 + n * 16 + lr;
        float bv = bias[col0 + d_loc];
        v4bf pv = {(__bf16)(acc[mm][n][0] + bv), (__bf16)(acc[mm][n][1] + bv),
                   (__bf16)(acc[mm][n][2] + bv), (__bf16)(acc[mm][n][3] + bv)};
        *(v4bf*)&lds[d_loc * 40 + wm16 + lg * 4] = pv;
      }
      __syncthreads();
      size_t vbase = ((size_t)((bb * NHEAD + hh) * DHEAD + dd)) * T_SEQ
                   + t0 + mm * 32 + half * 16;
      v8bf x0 = *(const v8bf*)&lds[d_r * 40 + half * 16];
      v8bf x1 = *(const v8bf*)&lds[d_r * 40 + half * 16 + 8];
      *(v8bf*)&Vt[vbase] = x0;
      *(v8bf*)&Vt[vbase + 8] = x1;
    }
    return;
  }

  // ---- Q/K blocks: fused bias + RoPE (table), lane-per-column-pair ----
  __syncthreads();   // ALL waves past vmcnt(0): stale tail glds landed in lds
  // stage acc+bias -> swizzled LDS tile [256 rows][512 B]; byte (2c)^((r&31)<<4)
#pragma unroll
  for (int n = 0; n < 4; ++n) {
    int c_loc = wn64 + n * 16 + lr;
    float bv = bias[col0 + c_loc];
#pragma unroll
    for (int mm = 0; mm < 8; ++mm) {
#pragma unroll
      for (int rr = 0; rr < 4; ++rr) {
        int r_loc = wm16 + mm * 32 + lg * 4 + rr;
        *(__bf16*)((char*)lds + r_loc * 512 + ((2 * c_loc) ^ ((r_loc & 31) << 4)))
            = (__bf16)(acc[mm][n][rr] + bv);
      }
    }
  }
  __syncthreads();
  {
    int tensor = col0 >> 11;                     // 0=Q, 1=K
    int h0 = (col0 & 2047) >> 7;
    int bb = row0 >> 11;
    int t0 = row0 & 2047;
    __bf16* QK = tensor ? Kb : Qb;
    int d = l;                                   // lane = output col pair (2d,2d+1)
    float sgn = (d < 32) ? -1.f : 1.f;           // cols<64: -cms ; cols>=64: +cms
    int mOff = 4 * d;                            // byte of x[2d] within head base
    int pOff = (d < 32) ? (8 * d) : (8 * d - 256);  // partner quad byte base
    int tOff = ((2 * d) & 63) * 8;               // table byte offset (j = c mod 64)
#pragma unroll 4
    for (int i = 0; i < 64; ++i) {
      int p = wid * 64 + i;                      // 0..511 (head-half, row)
      int u = p >> 8, r = p & 255;
      int tt = t0 + r;
      const char* lrow_ = (const char*)lds + r * 512;
      int swz = (r & 31) << 4;
      int cb = u * 256;
      v2bf xm = *(const v2bf*)(lrow_ + ((cb + mOff) ^ swz));   // x[2d], x[2d+1]
      v4bf xp = *(const v4bf*)(lrow_ + ((cb + pOff) ^ swz));   // partner quad
      float4 tv = *(const float4*)((const char*)(rt + (size_t)tt * 64) + tOff);
      float p1 = (d < 32) ? (float)xp[1] : (float)xp[0];       // x[2c1+1] | x[2c1-128]
      float p2 = (d < 32) ? (float)xp[3] : (float)xp[2];
      float o1 = (float)xm[0] * tv.x + sgn * p1 * tv.y;
      float o2 = (float)xm[1] * tv.z + sgn * p2 * tv.w;
      v2bf ov = {(__bf16)o1, (__bf16)o2};
      __bf16* dst = QK + ((size_t)(bb * NHEAD + h0 + u) * T_SEQ + tt) * DHEAD;
      *(v2bf*)(dst + 2 * d) = ov;
    }
  }
}

// GEMM2: out = Y * w_proj^T + b_proj, fp32 row-major epilogue; XCD-chunked map.
__global__ __launch_bounds__(512, 2) void gemm_out8(
    const __bf16* __restrict__ A, const __bf16* __restrict__ Bm,
    const float* __restrict__ bias, float* __restrict__ C) {
  extern __shared__ __bf16 lds[];
  int t = threadIdx.x, wid = t >> 6, l = t & 63;
  int lr = l & 15, lg = l >> 4;
  int wm16 = (wid >> 2) * 16, wn64 = (wid & 3) * 64;
  int bid = blockIdx.x;
  int xcd = bid & 7, idx = bid >> 3;            // 32 blocks per XCD
  int row0 = (xcd * 4 + idx / 8) * 256;
  int col0 = (idx % 8) * 256;
  v4f acc[8][4];
  gemm256_core(A, Bm, row0, col0, lds, acc, wm16, wn64, lr, lg);
#pragma unroll
  for (int n = 0; n < 4; ++n) {
    int col = col0 + wn64 + n * 16 + lr;
    float bv = bias[col];
#pragma unroll
    for (int mm = 0; mm < 8; ++mm) {
#pragma unroll
      for (int rr = 0; rr < 4; ++rr) {
        int mg = row0 + wm16 + mm * 32 + lg * 4 + rr;
        C[(size_t)mg * CDIM + col] = acc[mm][n][rr] + bv;
      }
    }
  }
}

// ---------------- flash attention v5 -----------------------------------------
// 512 thr = 8 waves, 256 q-rows/block; complementary CU pairing (r8);
// T14 reg-prefetch of next K/V tile (r9).
__global__ __launch_bounds__(512, 2) void attn_fwd(
    const __bf16* __restrict__ Qb, const __bf16* __restrict__ Kb,
    const __bf16* __restrict__ Vt, __bf16* __restrict__ Y) {
  __shared__ __bf16 lK[64 * 128];       // 16 KB, [kv][d] swizzled
  __shared__ __bf16 lV[128 * 64];       // 16 KB, [d][kv] swizzled
  __shared__ __bf16 plds[8][32][72];    // 36 KB, per-wave P, padded rows
  int t = threadIdx.x, w = t >> 6, l = t & 63;
  int lr = l & 15, lg = l >> 4;
  int id = blockIdx.x;                        // 0..511
  int xcd = id & 7, s = id >> 3;
  int bh = xcd * 8 + (s & 7);
  int g = s >> 3;
  int k = (g < 4) ? (7 - g) : (g - 4);
  int qb = k * 256;
  int b = bh >> 4, h = bh & 15;
  int q0 = qb + w * 32;
  const __bf16* Qh = Qb + (size_t)bh * T_SEQ * DHEAD;
  const __bf16* Kh = Kb + (size_t)bh * T_SEQ * DHEAD;
  const __bf16* Vh = Vt + (size_t)bh * DHEAD * T_SEQ;

  v8bf qf[2][4];
#pragma unroll
  for (int j = 0; j < 2; ++j)
#pragma unroll
    for (int c = 0; c < 4; ++c)
      qf[j][c] = *(const v8bf*)&Qh[(size_t)(q0 + j * 16 + lr) * DHEAD + c * 32 + lg * 8];

  v4f o[2][8];
#pragma unroll
  for (int j = 0; j < 2; ++j)
#pragma unroll
    for (int c = 0; c < 8; ++c) o[j][c] = (v4f){0.f, 0.f, 0.f, 0.f};
  float mrow[2] = {-1e30f, -1e30f}, lrow[2] = {0.f, 0.f};
  const float SCALE2 = 0.12751743f;   // (1/sqrt(128)) * log2(e)

  int kRow = t >> 4;                                       // 0..31
  int kSrc = (((t & 15) * 16) ^ ((kRow & 7) << 4)) >> 1;
  int vRow = t >> 3;                                       // 0..63
  int vSrc = (((t & 7) * 16) ^ ((vRow & 7) << 4)) >> 1;
  __bf16* lKd0 = lK + w * 512 + l * 8;
  __bf16* lKd1 = lK + 4096 + w * 512 + l * 8;
  __bf16* lVd0 = lV + w * 512 + l * 8;
  __bf16* lVd1 = lV + 4096 + w * 512 + l * 8;

  // prologue: tile 0 -> regs
  v8bf kr0 = *(const v8bf*)&Kh[(size_t)(kRow) * DHEAD + kSrc];
  v8bf kr1 = *(const v8bf*)&Kh[(size_t)(32 + kRow) * DHEAD + kSrc];
  v8bf vr0 = *(const v8bf*)&Vh[(size_t)(vRow) * T_SEQ + vSrc];
  v8bf vr1 = *(const v8bf*)&Vh[(size_t)(64 + vRow) * T_SEQ + vSrc];

  int kvEnd = qb + 192;
  for (int kv0 = 0; kv0 <= kvEnd; kv0 += 64) {
    __syncthreads();                       // prior tile fully consumed
    *(v8bf*)lKd0 = kr0; *(v8bf*)lKd1 = kr1;
    *(v8bf*)lVd0 = vr0; *(v8bf*)lVd1 = vr1;
    __syncthreads();                       // tile visible
    if (kv0 + 64 <= kvEnd) {               // prefetch next tile (wave-uniform)
      kr0 = *(const v8bf*)&Kh[(size_t)(kv0 + 64 + kRow) * DHEAD + kSrc];
      kr1 = *(const v8bf*)&Kh[(size_t)(kv0 + 96 + kRow) * DHEAD + kSrc];
      vr0 = *(const v8bf*)&Vh[(size_t)(vRow) * T_SEQ + kv0 + 64 + vSrc];
      vr1 = *(const v8bf*)&Vh[(size_t)(64 + vRow) * T_SEQ + kv0 + 64 + vSrc];
    }

    if (kv0 <= q0 + 31) {
      // ---- QK^T (swapped): S[64 kv][32 q] ----
      v4f s2[2][4];
#pragma unroll
      for (int j = 0; j < 2; ++j)
#pragma unroll
        for (int f = 0; f < 4; ++f) s2[j][f] = (v4f){0.f, 0.f, 0.f, 0.f};
#pragma unroll
      for (int f = 0; f < 4; ++f) {
        int row = f * 16 + lr;
        int sw = (row & 7) << 4;
#pragma unroll
        for (int c = 0; c < 4; ++c) {
          v8bf kf = *(const v8bf*)((const char*)lK + row * 256 + ((c * 64 + lg * 16) ^ sw));
          s2[0][f] = MFMA16(kf, qf[0][c], s2[0][f]);
          s2[1][f] = MFMA16(kf, qf[1][c], s2[1][f]);
        }
      }

      v8bf pa[2][2];
#pragma unroll
      for (int j = 0; j < 2; ++j) {
        int qg = q0 + j * 16 + lr;
        bool needMask = (kv0 + 63 > q0 + j * 16);
        float p[16];
        float mt = -1e30f;
#pragma unroll
        for (int f = 0; f < 4; ++f)
#pragma unroll
          for (int r = 0; r < 4; ++r) {
            float v = s2[j][f][r] * SCALE2;
            if (needMask && (kv0 + f * 16 + lg * 4 + r > qg)) v = -1e30f;
            p[f * 4 + r] = v;
            mt = fmaxf(mt, v);
          }
        mt = fmaxf(mt, __shfl_xor(mt, 16));
        mt = fmaxf(mt, __shfl_xor(mt, 32));
        if (!__all(mt <= mrow[j] + 8.0f)) {      // rescale (rare after warmup)
          float mnew = fmaxf(mrow[j], mt);
          float corr = exp2f(mrow[j] - mnew);
          mrow[j] = mnew;
          lrow[j] *= corr;
          float cf[4];
#pragma unroll
          for (int r = 0; r < 4; ++r) cf[r] = __shfl(corr, lg * 4 + r);
#pragma unroll
          for (int c = 0; c < 8; ++c)
#pragma unroll
            for (int r = 0; r < 4; ++r) o[j][c][r] *= cf[r];
        }
        float psum = 0.f;
#pragma unroll
        for (int r = 0; r < 16; ++r) { p[r] = exp2f(p[r] - mrow[j]); psum += p[r]; }
        psum += __shfl_xor(psum, 16);
        psum += __shfl_xor(psum, 32);
        lrow[j] += psum;
#pragma unroll
        for (int f = 0; f < 4; ++f) {
          v4bf pv = {(__bf16)p[f * 4], (__bf16)p[f * 4 + 1],
                     (__bf16)p[f * 4 + 2], (__bf16)p[f * 4 + 3]};
          *(v4bf*)&plds[w][j * 16 + lr][f * 16 + lg * 4] = pv;
        }
        asm volatile("s_waitcnt lgkmcnt(0)" ::: "memory");
        pa[j][0] = *(const v8bf*)&plds[w][j * 16 + lr][lg * 8];
        pa[j][1] = *(const v8bf*)&plds[w][j * 16 + lr][32 + lg * 8];
      }

      // ---- PV ----
#pragma unroll
      for (int c = 0; c < 8; ++c) {
        int row = c * 16 + lr;
        int sw = (row & 7) << 4;
        v8bf vf0 = *(const v8bf*)((const char*)lV + row * 128 + ((lg * 16) ^ sw));
        v8bf vf1 = *(const v8bf*)((const char*)lV + row * 128 + ((64 + lg * 16) ^ sw));
        o[0][c] = MFMA16(pa[0][0], vf0, o[0][c]);
        o[0][c] = MFMA16(pa[0][1], vf1, o[0][c]);
        o[1][c] = MFMA16(pa[1][0], vf0, o[1][c]);
        o[1][c] = MFMA16(pa[1][1], vf1, o[1][c]);
      }
    }
  }

  size_t ybase = ((size_t)b * T_SEQ) * CDIM + (size_t)h * DHEAD;
#pragma unroll
  for (int j = 0; j < 2; ++j) {
    float lf[4];
#pragma unroll
    for (int r = 0; r < 4; ++r) lf[r] = __shfl(lrow[j], lg * 4 + r);
#pragma unroll
    for (int c = 0; c < 8; ++c) {
#pragma unroll
      for (int r = 0; r < 4; ++r) {
        int qq = q0 + j * 16 + lg * 4 + r;
        Y[ybase + (size_t)qq * CDIM + c * 16 + lr] = (__bf16)(o[j][c][r] / lf[r]);
      }
    }
  }
}

// ---------------- launch -----------------------------------------------------
extern "C" void kernel_launch(void* const* d_in, const int* in_sizes, int n_in,
                              void* d_out, int out_size, void* d_ws, size_t ws_size,
                              hipStream_t stream) {
  const float* x      = (const float*)d_in[0];
  const float* w_attn = (const float*)d_in[1];
  const float* b_attn = (const float*)d_in[2];
  const float* w_proj = (const float*)d_in[3];
  const float* b_proj = (const float*)d_in[4];
  float* out = (float*)d_out;

  char* ws = (char*)d_ws;
  __bf16* xbf  = (__bf16*)(ws);                 // 33,554,432 B; reused as Y
  __bf16* wabf = (__bf16*)(ws + 33554432);      // 25,165,824 B
  __bf16* wpbf = (__bf16*)(ws + 58720256);      //  8,388,608 B
  __bf16* Qb   = (__bf16*)(ws + 67108864);      // 33,554,432 B (BH,T,D)
  __bf16* Kb   = (__bf16*)(ws + 100663296);     // 33,554,432 B (BH,T,D)
  __bf16* Vt   = (__bf16*)(ws + 134217728);     // 33,554,432 B (BH,D,T)
  float2* rtab = (float2*)(ws + 167772160);     //  1,048,576 B rope table
  __bf16* Y    = xbf;

  (void)hipFuncSetAttribute((const void*)gemm_qkv8,
                            hipFuncAttributeMaxDynamicSharedMemorySize, 131072);
  (void)hipFuncSetAttribute((const void*)gemm_out8,
                            hipFuncAttributeMaxDynamicSharedMemorySize, 131072);

  cvt_all<<<2048, 256, 0, stream>>>(x, w_attn, w_proj, xbf, wabf, wpbf, rtab);

  gemm_qkv8<<<768, 512, 131072, stream>>>(xbf, wabf, b_attn, rtab, Qb, Kb, Vt);

  attn_fwd<<<512, 512, 0, stream>>>(Qb, Kb, Vt, Y);

  gemm_out8<<<256, 512, 131072, stream>>>(Y, wpbf, b_proj, out);
}